// Round 5
// baseline (305.813 us; speedup 1.0000x reference)
//
#include <hip/hip_runtime.h>
#include <stdint.h>

#define NE 4096
#define FD 512
#define NCELLS 39
#define NPAIRS 8192
#define NT (FD / 64)  // 8 K-tiles of BK=64

typedef __attribute__((ext_vector_type(8))) short short8;
typedef __attribute__((ext_vector_type(8))) unsigned short ushort8;
typedef __attribute__((ext_vector_type(4))) float f32x4;
typedef __attribute__((ext_vector_type(4))) unsigned int uint4v;

__device__ __forceinline__ unsigned short f2bf(float f) {
  union { float f; uint32_t u; } v; v.f = f;
  uint32_t u = v.u;
  return (unsigned short)((u + 0x7fffu + ((u >> 16) & 1u)) >> 16);  // RNE
}
__device__ __forceinline__ float bf2f(unsigned short b) {
  return __uint_as_float(((uint32_t)b) << 16);
}

__device__ __forceinline__ void async16(const void* g, void* l) {
  __builtin_amdgcn_global_load_lds((const __attribute__((address_space(1))) void*)g,
                                   (__attribute__((address_space(3))) void*)l, 16, 0, 0);
}

// ---- kernel 1: embedding fp32 -> bf16 ----
__global__ __launch_bounds__(256) void conv_e(const float* __restrict__ E,
                                              unsigned short* __restrict__ Ebf) {
  const int i = blockIdx.x * 256 + threadIdx.x;
  const float4 v = ((const float4*)E)[i];
  ushort4 o;
  o.x = f2bf(v.x); o.y = f2bf(v.y); o.z = f2bf(v.z); o.w = f2bf(v.w);
  ((ushort4*)Ebf)[i] = o;
}

// ---- kernel 2: Wt[ci][k][n] = wl[c,n] * wl[c,k] * W[n,k], bf16, transposed ----
__global__ __launch_bounds__(256) void prep_w(const float* __restrict__ W,
                                              const float* __restrict__ wl,
                                              unsigned short* __restrict__ Wt,
                                              int c0) {
  __shared__ float tile[32][33];
  const int ci = blockIdx.z;
  const int tn = blockIdx.x * 32, tk = blockIdx.y * 32;
  const int tx = threadIdx.x & 31, ty = threadIdx.x >> 5;
  const float* wlr = wl + (size_t)(c0 + ci) * FD;
#pragma unroll
  for (int i = 0; i < 4; i++) {
    int n = tn + ty + i * 8;
    tile[ty + i * 8][tx] = W[(size_t)n * FD + tk + tx] * wlr[n];
  }
  __syncthreads();
  unsigned short* dst = Wt + (size_t)ci * FD * FD;
#pragma unroll
  for (int i = 0; i < 4; i++) {
    int kout = tk + ty + i * 8;
    dst[(size_t)kout * FD + tn + tx] = f2bf(tile[tx][ty + i * 8] * wlr[kout]);
  }
}

// ---- kernel 3 (FUSED): gemm 256x256 tile -> U tile kept in LDS -> in-block dot ----
// K-loop identical to round-2 best (8-phase, swizzled, vmcnt(4)).  U never
// touches global memory: acc -> LDS (128KB, granule-XOR swizzle), then scan the
// cell's index for pairs with i0 in this block's row range and dot against the
// Ebf column-slice [by*256, by*256+256).  partial[by][c][p] written exactly once
// per slot (no atomics, no zero-init); comb_k adds the two halves.
__global__ __launch_bounds__(512, 2) void gemm_f(const unsigned short* __restrict__ Ebf,
                                                 const unsigned short* __restrict__ Wt,
                                                 const int* __restrict__ index,
                                                 float* __restrict__ partial) {
  __shared__ unsigned short lds[2][2][2][128 * 64];  // K-loop staging; reused as U tile
  __shared__ int2 queue[2048];
  __shared__ int qcnt;

  const int t = threadIdx.x;
  const int id = blockIdx.x;
  // round-2 best mapping: id&7 = XCD, bx pinned per XCD
  const int xcd = id & 7;
  const int j = id >> 3;            // 0..155
  const int bx = xcd * 2 + (j & 1); // 0..15
  const int by = (j >> 1) & 1;
  const int ci = j >> 2;            // 0..38

  const unsigned short* Ag = Ebf + (size_t)bx * 256 * FD;
  const unsigned short* Bg = Wt + (size_t)ci * FD * FD + (size_t)by * 256 * FD;

  const int wave = t >> 6, lane = t & 63;
  const int wm = wave >> 2, wn = wave & 3;  // 2M x 4N wave grid
  const int lr = lane & 15, lq = lane >> 4;

  // staging: physical granule pg (row=pg>>3, g=pg&7); source uses g ^ (row&7)
  const int pg0 = t, pg1 = 512 + t;
  const int sr0 = pg0 >> 3, sg0 = pg0 & 7;
  const int sr1 = pg1 >> 3, sg1 = pg1 & 7;
  const int soff0 = sr0 * FD + ((sg0 ^ (sr0 & 7)) << 3);
  const int soff1 = sr1 * FD + ((sg1 ^ (sr1 & 7)) << 3);
  const int loff0 = pg0 * 8, loff1 = pg1 * 8;

  const int swz0 = (lq ^ (lr & 7)) << 3;        // k-slice 0 granule
  const int swz1 = ((4 + lq) ^ (lr & 7)) << 3;  // k-slice 1 granule

#define STAGE(OP, HALF, KT, GBASE)                                                \
  do {                                                                            \
    const int bi_ = (KT) & 1;                                                     \
    const int kt_ = (KT) < NT ? (KT) : (NT - 1);                                  \
    const unsigned short* gb_ = (GBASE) + (size_t)(HALF) * (128 * FD) + kt_ * 64; \
    unsigned short* d_ = &lds[bi_][OP][HALF][0];                                  \
    async16(gb_ + soff0, d_ + loff0);                                             \
    async16(gb_ + soff1, d_ + loff1);                                             \
  } while (0)

  short8 a[8], b01[4], b23[4];
  f32x4 acc[8][4];
#pragma unroll
  for (int i = 0; i < 8; i++)
#pragma unroll
    for (int j2 = 0; j2 < 4; j2++) acc[i][j2] = (f32x4){0.f, 0.f, 0.f, 0.f};

#define LDA(BUF, MSET)                                                  \
  do {                                                                  \
    const unsigned short* p_ = &lds[BUF][0][wm][0];                     \
    _Pragma("unroll") for (int mi_ = 0; mi_ < 4; ++mi_) {               \
      const int row_ = (MSET) * 64 + mi_ * 16 + lr;                     \
      a[mi_ * 2 + 0] = *(const short8*)&p_[row_ * 64 + swz0];           \
      a[mi_ * 2 + 1] = *(const short8*)&p_[row_ * 64 + swz1];           \
    }                                                                   \
  } while (0)

#define LDB(BUF, NSET, DST)                                             \
  do {                                                                  \
    const unsigned short* p_ = &lds[BUF][1][wn >> 1][0];                \
    _Pragma("unroll") for (int ni_ = 0; ni_ < 2; ++ni_) {               \
      const int row_ = (wn & 1) * 64 + ((NSET) * 2 + ni_) * 16 + lr;    \
      (DST)[ni_ * 2 + 0] = *(const short8*)&p_[row_ * 64 + swz0];       \
      (DST)[ni_ * 2 + 1] = *(const short8*)&p_[row_ * 64 + swz1];       \
    }                                                                   \
  } while (0)

#define MMA(MSET, NSET, B)                                                               \
  do {                                                                                   \
    __builtin_amdgcn_s_setprio(1);                                                       \
    _Pragma("unroll") for (int mi_ = 0; mi_ < 4; ++mi_)                                  \
    _Pragma("unroll") for (int ni_ = 0; ni_ < 2; ++ni_)                                  \
    _Pragma("unroll") for (int s_ = 0; s_ < 2; ++s_)                                     \
      acc[(MSET) * 4 + mi_][(NSET) * 2 + ni_] = __builtin_amdgcn_mfma_f32_16x16x32_bf16( \
          a[mi_ * 2 + s_], (B)[ni_ * 2 + s_],                                            \
          acc[(MSET) * 4 + mi_][(NSET) * 2 + ni_], 0, 0, 0);                             \
    __builtin_amdgcn_s_setprio(0);                                                       \
  } while (0)

#define SYNC_LG()                                        \
  do {                                                   \
    __builtin_amdgcn_s_barrier();                        \
    asm volatile("s_waitcnt lgkmcnt(0)" ::: "memory");   \
  } while (0)

  // prologue
  STAGE(1, 0, 0, Bg); STAGE(0, 0, 0, Ag); STAGE(1, 1, 0, Bg); STAGE(0, 1, 0, Ag);
  STAGE(1, 0, 1, Bg); STAGE(0, 0, 1, Ag);
  asm volatile("s_waitcnt vmcnt(4)" ::: "memory");
  __builtin_amdgcn_s_barrier();

  for (int it = 0; it < NT / 2; ++it) {
    const int k1 = 2 * it + 1, k2 = 2 * it + 2, k3 = 2 * it + 3;
    LDA(0, 0); LDB(0, 0, b01);
    STAGE(1, 1, k1, Bg);
    SYNC_LG(); MMA(0, 0, b01); __builtin_amdgcn_s_barrier();
    LDB(0, 1, b23);
    STAGE(0, 1, k1, Ag);
    SYNC_LG(); MMA(0, 1, b23); __builtin_amdgcn_s_barrier();
    LDA(0, 1);
    STAGE(1, 0, k2, Bg);
    SYNC_LG(); MMA(1, 1, b23); __builtin_amdgcn_s_barrier();
    STAGE(0, 0, k2, Ag);
    __builtin_amdgcn_s_barrier();
    MMA(1, 0, b01);
    asm volatile("s_waitcnt vmcnt(4)" ::: "memory");
    __builtin_amdgcn_s_barrier();
    LDA(1, 0); LDB(1, 0, b01);
    STAGE(1, 1, k2, Bg);
    SYNC_LG(); MMA(0, 0, b01); __builtin_amdgcn_s_barrier();
    LDB(1, 1, b23);
    STAGE(0, 1, k2, Ag);
    SYNC_LG(); MMA(0, 1, b23); __builtin_amdgcn_s_barrier();
    LDA(1, 1);
    STAGE(1, 0, k3, Bg);
    SYNC_LG(); MMA(1, 1, b23); __builtin_amdgcn_s_barrier();
    STAGE(0, 0, k3, Ag);
    __builtin_amdgcn_s_barrier();
    MMA(1, 0, b01);
    asm volatile("s_waitcnt vmcnt(4)" ::: "memory");
    __builtin_amdgcn_s_barrier();
  }

  // ---- drain staging DMA (clamped refetches may still be in flight), then
  //      repurpose LDS as the U tile ----
  asm volatile("s_waitcnt vmcnt(0)" ::: "memory");
  __syncthreads();

  // acc -> LDS bf16 [256][256], granule-XOR swizzle: elem' = col ^ ((row&12)<<2).
  // Write: per instruction the 4 lq-row-groups land in 4 disjoint 32B regions
  // covering all 32 banks at 2 lanes/bank (free).  Read: full-row, full-BW.
  unsigned short* Ut = &lds[0][0][0][0];
  {
    const int mrow0w = wm * 128, ncol0w = wn * 64;
#pragma unroll
    for (int mi = 0; mi < 8; ++mi)
#pragma unroll
      for (int ni = 0; ni < 4; ++ni)
#pragma unroll
        for (int r = 0; r < 4; ++r) {
          const int row = mrow0w + mi * 16 + lq * 4 + r;
          const int col = ncol0w + ni * 16 + lr;
          Ut[row * 256 + (col ^ ((row & 12) << 2))] = f2bf(acc[mi][ni][r]);
        }
  }
  __syncthreads();

  // ---- scan index + in-block dot ----
  const int2* idxc = (const int2*)index + (size_t)ci * NPAIRS;
  const unsigned short* Eslice = Ebf + by * 256;
  float* pc = partial + ((size_t)by * NCELLS + ci) * NPAIRS;
  const int b1 = lane & 1, b2 = (lane >> 1) & 1, b4 = (lane >> 2) & 1;

  for (int seg = 0; seg < NPAIRS; seg += 2048) {
    if (t == 0) qcnt = 0;
    __syncthreads();
#pragma unroll
    for (int k2 = 0; k2 < 4; ++k2) {
      const int e = seg + t + k2 * 512;
      const int2 ie = idxc[e];
      if ((ie.x >> 8) == bx) {
        const int pos = atomicAdd(&qcnt, 1);
        queue[pos] = make_int2(e, (ie.y << 8) | (ie.x & 255));
      }
    }
    __syncthreads();
    const int cnt = qcnt;
    for (int base = wave * 8; base < cnt; base += 64) {
      float v[8];
#pragma unroll
      for (int jj = 0; jj < 8; ++jj) {
        float s = 0.f;
        const int item = base + jj;
        if (item < cnt) {
          const int2 qe = queue[item];
          const int i0l = qe.y & 255;
          const int i1 = qe.y >> 8;
          const ushort4 uu =
              *(const ushort4*)&Ut[i0l * 256 + ((lane * 4) ^ ((i0l & 12) << 2))];
          const ushort4 ee = *(const ushort4*)&Eslice[(size_t)i1 * FD + lane * 4];
          s = bf2f(uu.x) * bf2f(ee.x) + bf2f(uu.y) * bf2f(ee.y) +
              bf2f(uu.z) * bf2f(ee.z) + bf2f(uu.w) * bf2f(ee.w);
        }
        v[jj] = s;
      }
      // transpose-butterfly: fold pair bits into lane bits (xor 1,2,4), then reduce
      float w[4];
#pragma unroll
      for (int q = 0; q < 4; ++q) {
        const float keep = b1 ? v[2 * q + 1] : v[2 * q];
        const float send = b1 ? v[2 * q] : v[2 * q + 1];
        w[q] = keep + __shfl_xor(send, 1, 64);
      }
      float u2[2];
#pragma unroll
      for (int q = 0; q < 2; ++q) {
        const float keep = b2 ? w[2 * q + 1] : w[2 * q];
        const float send = b2 ? w[2 * q] : w[2 * q + 1];
        u2[q] = keep + __shfl_xor(send, 2, 64);
      }
      float f;
      {
        const float keep = b4 ? u2[1] : u2[0];
        const float send = b4 ? u2[0] : u2[1];
        f = keep + __shfl_xor(send, 4, 64);
      }
      f += __shfl_xor(f, 8, 64);
      f += __shfl_xor(f, 16, 64);
      f += __shfl_xor(f, 32, 64);
      if (lane < 8 && base + lane < cnt) {
        const int p = queue[base + lane].x;
        pc[p] = f;
      }
    }
    __syncthreads();
  }
#undef STAGE
#undef LDA
#undef LDB
#undef MMA
#undef SYNC_LG
}

// ---- kernel 4: out = partial(by=0) + partial(by=1) ----
__global__ __launch_bounds__(256) void comb_k(const float* __restrict__ partial,
                                              float* __restrict__ out) {
  const int i = blockIdx.x * 256 + threadIdx.x;
  out[i] = partial[i] + partial[(size_t)NCELLS * NPAIRS + i];
}

// ---- fallback (tiny workspace): direct fp32, slow but correct ----
__global__ __launch_bounds__(256) void naive_k(const float* __restrict__ emb,
                                               const int* __restrict__ index,
                                               const float* __restrict__ W,
                                               const float* __restrict__ wl,
                                               float* __restrict__ out) {
  __shared__ float bs[FD];
  __shared__ float red[256];
  const int c = blockIdx.y, p = blockIdx.x;
  const int i0 = index[((size_t)c * NPAIRS + p) * 2];
  const int i1 = index[((size_t)c * NPAIRS + p) * 2 + 1];
  const float* wlc = wl + (size_t)c * FD;
  for (int k = threadIdx.x; k < FD; k += 256) bs[k] = emb[(size_t)i1 * FD + k] * wlc[k];
  __syncthreads();
  float s = 0.f;
  for (int n = threadIdx.x; n < FD; n += 256) {
    const float* wr = W + (size_t)n * FD;
    float tacc = 0.f;
    for (int k = 0; k < FD; k++) tacc += wr[k] * bs[k];
    s += tacc * emb[(size_t)i0 * FD + n] * wlc[n];
  }
  red[threadIdx.x] = s;
  __syncthreads();
  for (int st = 128; st > 0; st >>= 1) {
    if (threadIdx.x < st) red[threadIdx.x] += red[threadIdx.x + st];
    __syncthreads();
  }
  if (threadIdx.x == 0) out[(size_t)c * NPAIRS + p] = red[0];
}

extern "C" void kernel_launch(void* const* d_in, const int* in_sizes, int n_in,
                              void* d_out, int out_size, void* d_ws, size_t ws_size,
                              hipStream_t stream) {
  const float* emb = (const float*)d_in[0];
  const int* index = (const int*)d_in[1];
  const float* Wg = (const float*)d_in[2];
  const float* wl = (const float*)d_in[3];
  float* out = (float*)d_out;

  const size_t ebytes = (size_t)NE * FD * 2;                  // 4 MiB bf16 embedding
  const size_t wtbytes = (size_t)NCELLS * FD * FD * 2;        // 19.5 MiB Wt
  const size_t pbytes = (size_t)2 * NCELLS * NPAIRS * 4;      // 2.5 MiB partials
  if (ws_size < ebytes + wtbytes + pbytes) {
    naive_k<<<dim3(NPAIRS, NCELLS), 256, 0, stream>>>(emb, index, Wg, wl, out);
    return;
  }

  unsigned short* Ebf = (unsigned short*)d_ws;
  unsigned short* Wt = (unsigned short*)((char*)d_ws + ebytes);
  float* partial = (float*)((char*)d_ws + ebytes + wtbytes);

  conv_e<<<dim3((NE * FD / 4) / 256), 256, 0, stream>>>(emb, Ebf);
  prep_w<<<dim3(FD / 32, FD / 32, NCELLS), 256, 0, stream>>>(Wg, wl, Wt, 0);
  // 1248 blocks: id&7 = XCD, bx pinned per XCD (round-2 best mapping)
  gemm_f<<<dim3(4 * NCELLS * 8), 512, 0, stream>>>(Ebf, Wt, index, partial);
  comb_k<<<dim3(NCELLS * NPAIRS / 256), 256, 0, stream>>>(partial, out);
}

// Round 6
// 240.438 us; speedup vs baseline: 1.2719x; 1.2719x over previous
//
#include <hip/hip_runtime.h>
#include <stdint.h>

#define NE 4096
#define FD 512
#define NCELLS 39
#define NPAIRS 8192
#define NT (FD / 64)  // 8 K-tiles of BK=64

typedef __attribute__((ext_vector_type(8))) short short8;
typedef __attribute__((ext_vector_type(8))) unsigned short ushort8;
typedef __attribute__((ext_vector_type(4))) float f32x4;
typedef __attribute__((ext_vector_type(4))) unsigned int uint4v;

__device__ __forceinline__ unsigned short f2bf(float f) {
  union { float f; uint32_t u; } v; v.f = f;
  uint32_t u = v.u;
  return (unsigned short)((u + 0x7fffu + ((u >> 16) & 1u)) >> 16);  // RNE
}
__device__ __forceinline__ float bf2f(unsigned short b) {
  return __uint_as_float(((uint32_t)b) << 16);
}

__device__ __forceinline__ void async16(const void* g, void* l) {
  __builtin_amdgcn_global_load_lds((const __attribute__((address_space(1))) void*)g,
                                   (__attribute__((address_space(3))) void*)l, 16, 0, 0);
}

// ---- kernel 1: embedding fp32 -> bf16 ----
__global__ __launch_bounds__(256) void conv_e(const float* __restrict__ E,
                                              unsigned short* __restrict__ Ebf) {
  const int i = blockIdx.x * 256 + threadIdx.x;
  const float4 v = ((const float4*)E)[i];
  ushort4 o;
  o.x = f2bf(v.x); o.y = f2bf(v.y); o.z = f2bf(v.z); o.w = f2bf(v.w);
  ((ushort4*)Ebf)[i] = o;
}

// ---- kernel 2: Wt[ci][k][n] = wl[c,n] * wl[c,k] * W[n,k], bf16, transposed ----
__global__ __launch_bounds__(256) void prep_w(const float* __restrict__ W,
                                              const float* __restrict__ wl,
                                              unsigned short* __restrict__ Wt,
                                              int c0) {
  __shared__ float tile[32][33];
  const int ci = blockIdx.z;
  const int tn = blockIdx.x * 32, tk = blockIdx.y * 32;
  const int tx = threadIdx.x & 31, ty = threadIdx.x >> 5;
  const float* wlr = wl + (size_t)(c0 + ci) * FD;
#pragma unroll
  for (int i = 0; i < 4; i++) {
    int n = tn + ty + i * 8;
    tile[ty + i * 8][tx] = W[(size_t)n * FD + tk + tx] * wlr[n];
  }
  __syncthreads();
  unsigned short* dst = Wt + (size_t)ci * FD * FD;
#pragma unroll
  for (int i = 0; i < 4; i++) {
    int kout = tk + ty + i * 8;
    dst[(size_t)kout * FD + tn + tx] = f2bf(tile[tx][ty + i * 8] * wlr[kout]);
  }
}

// ---- kernel 3: U[ci][e][k] = sum_n Ebf[e,n] * Wt[ci][k][n]  (bf16 out) ----
// 256x256 8-phase template (round-2 proven).  NEW: L2-window block mapping.
// Consecutive ids round-robin XCDs (id&7).  Bit layout makes each XCD's 32
// concurrent blocks tile an 8bx x 4(ci,by) rectangle: L2 working set =
// 8 A-panels (2MB) + 4 B-panels (1MB) = 3MB < 4MiB XCD L2 (was 4.5MB ->
// B streamed from L3 every block; measured 640MB staging @ ~6 TB/s = limiter).
__global__ __launch_bounds__(512, 2) void gemm_k(const unsigned short* __restrict__ Ebf,
                                                 const unsigned short* __restrict__ Wt,
                                                 unsigned short* __restrict__ U) {
  __shared__ unsigned short lds[2][2][2][128 * 64];  // [buf][A=0/B=1][half][row*64+col]
  const int t = threadIdx.x;
  const int id = blockIdx.x;
  int bx, by, ci;
  if (gridDim.x == 32 * NCELLS) {
    // full dispatch (1248 blocks): window-256 L2-tiled mapping (bijective)
    if (id < 1024) {
      const int a = id & 7, m = (id >> 3) & 7, h = (id >> 6) & 3, w = id >> 8;
      bx = m | ((a & 1) << 3);
      const int cb = (w << 4) | ((a >> 1) << 2) | h;  // 0..63
      ci = cb >> 1; by = cb & 1;
    } else {
      const int r = id - 1024;  // 0..223 tail: 14 cb x 16 bx
      bx = r & 15;
      const int cb = 64 + (r >> 4);  // 64..77
      ci = cb >> 1; by = cb & 1;
    }
  } else {
    // chunked fallback: round-2 generic mapping (bx pinned per XCD)
    const int xcd = id & 7;
    const int j = id >> 3;
    bx = xcd * 2 + (j & 1);
    by = (j >> 1) & 1;
    ci = j >> 2;
  }

  const unsigned short* Ag = Ebf + (size_t)bx * 256 * FD;
  const unsigned short* Bg = Wt + (size_t)ci * FD * FD + (size_t)by * 256 * FD;

  const int wave = t >> 6, lane = t & 63;
  const int wm = wave >> 2, wn = wave & 3;  // 2M x 4N wave grid
  const int lr = lane & 15, lq = lane >> 4;

  // staging: physical granule pg (row=pg>>3, g=pg&7); source uses g ^ (row&7)
  const int pg0 = t, pg1 = 512 + t;
  const int sr0 = pg0 >> 3, sg0 = pg0 & 7;
  const int sr1 = pg1 >> 3, sg1 = pg1 & 7;
  const int soff0 = sr0 * FD + ((sg0 ^ (sr0 & 7)) << 3);
  const int soff1 = sr1 * FD + ((sg1 ^ (sr1 & 7)) << 3);
  const int loff0 = pg0 * 8, loff1 = pg1 * 8;

  // read swizzle: frag rows always have row%8 == lr%8
  const int swz0 = (lq ^ (lr & 7)) << 3;        // k-slice 0 granule
  const int swz1 = ((4 + lq) ^ (lr & 7)) << 3;  // k-slice 1 granule

#define STAGE(OP, HALF, KT, GBASE)                                                \
  do {                                                                            \
    const int bi_ = (KT) & 1;             /* buffer from UNclamped kt */          \
    const int kt_ = (KT) < NT ? (KT) : (NT - 1); /* clamp src, keep count */      \
    const unsigned short* gb_ = (GBASE) + (size_t)(HALF) * (128 * FD) + kt_ * 64; \
    unsigned short* d_ = &lds[bi_][OP][HALF][0];                                  \
    async16(gb_ + soff0, d_ + loff0);                                             \
    async16(gb_ + soff1, d_ + loff1);                                             \
  } while (0)

  short8 a[8], b01[4], b23[4];
  f32x4 acc[8][4];
#pragma unroll
  for (int i = 0; i < 8; i++)
#pragma unroll
    for (int j2 = 0; j2 < 4; j2++) acc[i][j2] = (f32x4){0.f, 0.f, 0.f, 0.f};

#define LDA(BUF, MSET)                                                  \
  do {                                                                  \
    const unsigned short* p_ = &lds[BUF][0][wm][0];                     \
    _Pragma("unroll") for (int mi_ = 0; mi_ < 4; ++mi_) {               \
      const int row_ = (MSET) * 64 + mi_ * 16 + lr;                     \
      a[mi_ * 2 + 0] = *(const short8*)&p_[row_ * 64 + swz0];           \
      a[mi_ * 2 + 1] = *(const short8*)&p_[row_ * 64 + swz1];           \
    }                                                                   \
  } while (0)

#define LDB(BUF, NSET, DST)                                             \
  do {                                                                  \
    const unsigned short* p_ = &lds[BUF][1][wn >> 1][0];                \
    _Pragma("unroll") for (int ni_ = 0; ni_ < 2; ++ni_) {               \
      const int row_ = (wn & 1) * 64 + ((NSET) * 2 + ni_) * 16 + lr;    \
      (DST)[ni_ * 2 + 0] = *(const short8*)&p_[row_ * 64 + swz0];       \
      (DST)[ni_ * 2 + 1] = *(const short8*)&p_[row_ * 64 + swz1];       \
    }                                                                   \
  } while (0)

#define MMA(MSET, NSET, B)                                                               \
  do {                                                                                   \
    __builtin_amdgcn_s_setprio(1);                                                       \
    _Pragma("unroll") for (int mi_ = 0; mi_ < 4; ++mi_)                                  \
    _Pragma("unroll") for (int ni_ = 0; ni_ < 2; ++ni_)                                  \
    _Pragma("unroll") for (int s_ = 0; s_ < 2; ++s_)                                     \
      acc[(MSET) * 4 + mi_][(NSET) * 2 + ni_] = __builtin_amdgcn_mfma_f32_16x16x32_bf16( \
          a[mi_ * 2 + s_], (B)[ni_ * 2 + s_],                                            \
          acc[(MSET) * 4 + mi_][(NSET) * 2 + ni_], 0, 0, 0);                             \
    __builtin_amdgcn_s_setprio(0);                                                       \
  } while (0)

#define SYNC_LG()                                        \
  do {                                                   \
    __builtin_amdgcn_s_barrier();                        \
    asm volatile("s_waitcnt lgkmcnt(0)" ::: "memory");   \
  } while (0)

  // prologue: all 4 half-tiles of kt0 + B-lo,A-lo of kt1 (6 HTs = 12 loads)
  STAGE(1, 0, 0, Bg); STAGE(0, 0, 0, Ag); STAGE(1, 1, 0, Bg); STAGE(0, 1, 0, Ag);
  STAGE(1, 0, 1, Bg); STAGE(0, 0, 1, Ag);
  asm volatile("s_waitcnt vmcnt(4)" ::: "memory");  // kt0 fully landed
  __builtin_amdgcn_s_barrier();

  for (int it = 0; it < NT / 2; ++it) {
    const int k1 = 2 * it + 1, k2 = 2 * it + 2, k3 = 2 * it + 3;
    // ----- K-tile 2it from buf0 -----
    LDA(0, 0); LDB(0, 0, b01);
    STAGE(1, 1, k1, Bg);
    SYNC_LG(); MMA(0, 0, b01); __builtin_amdgcn_s_barrier();
    LDB(0, 1, b23);
    STAGE(0, 1, k1, Ag);
    SYNC_LG(); MMA(0, 1, b23); __builtin_amdgcn_s_barrier();
    LDA(0, 1);
    STAGE(1, 0, k2, Bg);
    SYNC_LG(); MMA(1, 1, b23); __builtin_amdgcn_s_barrier();
    STAGE(0, 0, k2, Ag);
    __builtin_amdgcn_s_barrier();
    MMA(1, 0, b01);
    asm volatile("s_waitcnt vmcnt(4)" ::: "memory");  // kt1 fully landed
    __builtin_amdgcn_s_barrier();
    // ----- K-tile 2it+1 from buf1 -----
    LDA(1, 0); LDB(1, 0, b01);
    STAGE(1, 1, k2, Bg);
    SYNC_LG(); MMA(0, 0, b01); __builtin_amdgcn_s_barrier();
    LDB(1, 1, b23);
    STAGE(0, 1, k2, Ag);
    SYNC_LG(); MMA(0, 1, b23); __builtin_amdgcn_s_barrier();
    LDA(1, 1);
    STAGE(1, 0, k3, Bg);
    SYNC_LG(); MMA(1, 1, b23); __builtin_amdgcn_s_barrier();
    STAGE(0, 0, k3, Ag);
    __builtin_amdgcn_s_barrier();
    MMA(1, 0, b01);
    asm volatile("s_waitcnt vmcnt(4)" ::: "memory");  // kt2 fully landed
    __builtin_amdgcn_s_barrier();
  }

  // epilogue: C/D layout col=lane&15, row=(lane>>4)*4+reg
  unsigned short* Up = U + (size_t)ci * NE * FD;
  const int mrow0 = bx * 256 + wm * 128;
  const int ncol0 = by * 256 + wn * 64;
#pragma unroll
  for (int mi = 0; mi < 8; ++mi) {
    const int mbase = mrow0 + mi * 16 + lq * 4;
#pragma unroll
    for (int ni = 0; ni < 4; ++ni) {
      const int n = ncol0 + ni * 16 + lr;
#pragma unroll
      for (int r = 0; r < 4; ++r)
        Up[(size_t)(mbase + r) * FD + n] = f2bf(acc[mi][ni][r]);
    }
  }
#undef STAGE
#undef LDA
#undef LDB
#undef MMA
#undef SYNC_LG
}

// ---- kernel 4: out[c,p] = sum_k U[ci,i0,k] * Ebf[i1,k] ----
// Transpose-butterfly reduce: 10 shuffles per 8-pair batch, identical tree.
__global__ __launch_bounds__(256) void dot_k(const unsigned short* __restrict__ U,
                                             const unsigned short* __restrict__ Ebf,
                                             const int* __restrict__ index,
                                             float* __restrict__ out,
                                             int c0) {
  const int ci = blockIdx.y;
  const int c = c0 + ci;
  const int wave = threadIdx.x >> 6, lane = threadIdx.x & 63;
  const unsigned short* Uc = U + (size_t)ci * NE * FD;
  const size_t cp = (size_t)c * NPAIRS;
  const int2* idx2 = (const int2*)index + cp;
  float* op = out + cp;
  const int pbase = (blockIdx.x * 4 + wave) * 32;

  const int b1 = lane & 1, b2 = (lane >> 1) & 1, b4 = (lane >> 2) & 1;

  for (int batch = 0; batch < 4; batch++) {
    const int pb = pbase + batch * 8;
    int2 id[8];
#pragma unroll
    for (int b = 0; b < 8; b++) id[b] = idx2[pb + b];
    uint4v uv[8], ev[8];
#pragma unroll
    for (int b = 0; b < 8; b++) {
      uv[b] = *(const uint4v*)(Uc + (size_t)id[b].x * FD + lane * 8);
      ev[b] = *(const uint4v*)(Ebf + (size_t)id[b].y * FD + lane * 8);
    }
    float v[8];
#pragma unroll
    for (int b = 0; b < 8; b++) {
      const ushort8 u = *(const ushort8*)&uv[b];
      const ushort8 e = *(const ushort8*)&ev[b];
      float s = 0.f;
#pragma unroll
      for (int q = 0; q < 8; q++) s += bf2f(u[q]) * bf2f(e[q]);
      v[b] = s;
    }
    // fold pair-index bit 0 into lane bit 0
    float w[4];
#pragma unroll
    for (int q = 0; q < 4; q++) {
      const float keep = b1 ? v[2 * q + 1] : v[2 * q];
      const float send = b1 ? v[2 * q] : v[2 * q + 1];
      w[q] = keep + __shfl_xor(send, 1, 64);
    }
    // bit 1
    float u2[2];
#pragma unroll
    for (int q = 0; q < 2; q++) {
      const float keep = b2 ? w[2 * q + 1] : w[2 * q];
      const float send = b2 ? w[2 * q] : w[2 * q + 1];
      u2[q] = keep + __shfl_xor(send, 2, 64);
    }
    // bit 2
    float f;
    {
      const float keep = b4 ? u2[1] : u2[0];
      const float send = b4 ? u2[0] : u2[1];
      f = keep + __shfl_xor(send, 4, 64);
    }
    // pure reduction across 8-lane groups; lane l now holds pair (l&7)
    f += __shfl_xor(f, 8, 64);
    f += __shfl_xor(f, 16, 64);
    f += __shfl_xor(f, 32, 64);
    if (lane < 8) op[pb + lane] = f;
  }
}

// ---- fallback (tiny workspace): direct fp32, slow but correct ----
__global__ __launch_bounds__(256) void naive_k(const float* __restrict__ emb,
                                               const int* __restrict__ index,
                                               const float* __restrict__ W,
                                               const float* __restrict__ wl,
                                               float* __restrict__ out) {
  __shared__ float bs[FD];
  __shared__ float red[256];
  const int c = blockIdx.y, p = blockIdx.x;
  const int i0 = index[((size_t)c * NPAIRS + p) * 2];
  const int i1 = index[((size_t)c * NPAIRS + p) * 2 + 1];
  const float* wlc = wl + (size_t)c * FD;
  for (int k = threadIdx.x; k < FD; k += 256) bs[k] = emb[(size_t)i1 * FD + k] * wlc[k];
  __syncthreads();
  float s = 0.f;
  for (int n = threadIdx.x; n < FD; n += 256) {
    const float* wr = W + (size_t)n * FD;
    float tacc = 0.f;
    for (int k = 0; k < FD; k++) tacc += wr[k] * bs[k];
    s += tacc * emb[(size_t)i0 * FD + n] * wlc[n];
  }
  red[threadIdx.x] = s;
  __syncthreads();
  for (int st = 128; st > 0; st >>= 1) {
    if (threadIdx.x < st) red[threadIdx.x] += red[threadIdx.x + st];
    __syncthreads();
  }
  if (threadIdx.x == 0) out[(size_t)c * NPAIRS + p] = red[0];
}

extern "C" void kernel_launch(void* const* d_in, const int* in_sizes, int n_in,
                              void* d_out, int out_size, void* d_ws, size_t ws_size,
                              hipStream_t stream) {
  const float* emb = (const float*)d_in[0];
  const int* index = (const int*)d_in[1];
  const float* Wg = (const float*)d_in[2];
  const float* wl = (const float*)d_in[3];
  float* out = (float*)d_out;

  const size_t ebytes = (size_t)NE * FD * 2;  // 4 MiB bf16 embedding
  const size_t wtcell = (size_t)FD * FD * 2;  // 0.5 MiB per-cell Wt
  const size_t ucell = (size_t)NE * FD * 2;   // 4 MiB per-cell U
  size_t avail = ws_size > ebytes ? ws_size - ebytes : 0;
  int G = (int)(avail / (wtcell + ucell));
  if (G > NCELLS) G = NCELLS;

  if (G < 1) {
    naive_k<<<dim3(NPAIRS, NCELLS), 256, 0, stream>>>(emb, index, Wg, wl, out);
    return;
  }

  unsigned short* Ebf = (unsigned short*)d_ws;
  unsigned short* Wt = (unsigned short*)((char*)d_ws + ebytes);
  unsigned short* U = (unsigned short*)((char*)d_ws + ebytes + (size_t)G * wtcell);

  conv_e<<<dim3((NE * FD / 4) / 256), 256, 0, stream>>>(emb, Ebf);
  for (int c0 = 0; c0 < NCELLS; c0 += G) {
    int g = (NCELLS - c0 < G) ? (NCELLS - c0) : G;
    prep_w<<<dim3(FD / 32, FD / 32, g), 256, 0, stream>>>(Wg, wl, Wt, c0);
    // full dispatch: window-256 L2-tiled mapping; chunked: round-2 mapping
    gemm_k<<<dim3(32 * g), 512, 0, stream>>>(Ebf, Wt, U);
    dot_k<<<dim3(NPAIRS / 128, g), 256, 0, stream>>>(U, Ebf, index, out, c0);
  }
}

// Round 7
// 239.887 us; speedup vs baseline: 1.2748x; 1.0023x over previous
//
#include <hip/hip_runtime.h>
#include <stdint.h>

#define NE 4096
#define FD 512
#define NCELLS 39
#define NPAIRS 8192
#define NT (FD / 64)  // 8 K-tiles of BK=64

typedef __attribute__((ext_vector_type(8))) short short8;
typedef __attribute__((ext_vector_type(8))) unsigned short ushort8;
typedef __attribute__((ext_vector_type(4))) float f32x4;
typedef __attribute__((ext_vector_type(4))) unsigned int uint4v;

__device__ __forceinline__ unsigned short f2bf(float f) {
  union { float f; uint32_t u; } v; v.f = f;
  uint32_t u = v.u;
  return (unsigned short)((u + 0x7fffu + ((u >> 16) & 1u)) >> 16);  // RNE
}
__device__ __forceinline__ float bf2f(unsigned short b) {
  return __uint_as_float(((uint32_t)b) << 16);
}

__device__ __forceinline__ void async16(const void* g, void* l) {
  __builtin_amdgcn_global_load_lds((const __attribute__((address_space(1))) void*)g,
                                   (__attribute__((address_space(3))) void*)l, 16, 0, 0);
}

// ---- kernel 1 (merged): blocks [0,2048) convert embedding fp32->bf16;
//      blocks [2048,12032) build Wt[ci][k][n] = wl[c,n]*wl[c,k]*W[n,k] (bf16) ----
__global__ __launch_bounds__(256) void init_k(const float* __restrict__ E,
                                              unsigned short* __restrict__ Ebf,
                                              const float* __restrict__ W,
                                              const float* __restrict__ wl,
                                              unsigned short* __restrict__ Wt) {
  __shared__ float tile[32][33];
  const int bid = blockIdx.x;
  if (bid < 2048) {
    const int i = bid * 256 + threadIdx.x;
    const float4 v = ((const float4*)E)[i];
    ushort4 o;
    o.x = f2bf(v.x); o.y = f2bf(v.y); o.z = f2bf(v.z); o.w = f2bf(v.w);
    ((ushort4*)Ebf)[i] = o;
    return;
  }
  const int pid = bid - 2048;
  const int ci = pid >> 8;
  const int rem = pid & 255;
  const int tn = (rem & 15) * 32, tk = (rem >> 4) * 32;
  const int tx = threadIdx.x & 31, ty = threadIdx.x >> 5;
  const float* wlr = wl + (size_t)ci * FD;
#pragma unroll
  for (int i = 0; i < 4; i++) {
    int n = tn + ty + i * 8;
    tile[ty + i * 8][tx] = W[(size_t)n * FD + tk + tx] * wlr[n];
  }
  __syncthreads();
  unsigned short* dst = Wt + (size_t)ci * FD * FD;
#pragma unroll
  for (int i = 0; i < 4; i++) {
    int kout = tk + ty + i * 8;
    dst[(size_t)kout * FD + tn + tx] = f2bf(tile[tx][ty + i * 8] * wlr[kout]);
  }
}

// ---- standalone copies for the chunked fallback path ----
__global__ __launch_bounds__(256) void conv_e(const float* __restrict__ E,
                                              unsigned short* __restrict__ Ebf) {
  const int i = blockIdx.x * 256 + threadIdx.x;
  const float4 v = ((const float4*)E)[i];
  ushort4 o;
  o.x = f2bf(v.x); o.y = f2bf(v.y); o.z = f2bf(v.z); o.w = f2bf(v.w);
  ((ushort4*)Ebf)[i] = o;
}

__global__ __launch_bounds__(256) void prep_w(const float* __restrict__ W,
                                              const float* __restrict__ wl,
                                              unsigned short* __restrict__ Wt,
                                              int c0) {
  __shared__ float tile[32][33];
  const int ci = blockIdx.z;
  const int tn = blockIdx.x * 32, tk = blockIdx.y * 32;
  const int tx = threadIdx.x & 31, ty = threadIdx.x >> 5;
  const float* wlr = wl + (size_t)(c0 + ci) * FD;
#pragma unroll
  for (int i = 0; i < 4; i++) {
    int n = tn + ty + i * 8;
    tile[ty + i * 8][tx] = W[(size_t)n * FD + tk + tx] * wlr[n];
  }
  __syncthreads();
  unsigned short* dst = Wt + (size_t)ci * FD * FD;
#pragma unroll
  for (int i = 0; i < 4; i++) {
    int kout = tk + ty + i * 8;
    dst[(size_t)kout * FD + tn + tx] = f2bf(tile[tx][ty + i * 8] * wlr[kout]);
  }
}

// ---- kernel 3: U[ci][e][k] = sum_n Ebf[e,n] * Wt[ci][k][n]  (bf16 out) ----
// 256x256 8-phase template + window-256 L2-tiled mapping (round-6).
// NEW (round-7): LDS-bounce epilogue.  Old epilogue: 128 scattered 2B stores
// per lane (wave-store = 4x32B fragments -> ~5M write transactions competing
// with staging in L2, long serial tail at 1 block/CU).  New: drain DMA, dump
// acc into LDS [256][256] bf16 (granule-XOR swizzled, conflict-free both
// sides -- r5-verified scheme), then 16 coalesced ushort8 row-stores/thread.
__global__ __launch_bounds__(512, 2) void gemm_k(const unsigned short* __restrict__ Ebf,
                                                 const unsigned short* __restrict__ Wt,
                                                 unsigned short* __restrict__ U) {
  __shared__ unsigned short lds[2][2][2][128 * 64];  // [buf][A=0/B=1][half][row*64+col]
  const int t = threadIdx.x;
  const int id = blockIdx.x;
  int bx, by, ci;
  if (gridDim.x == 32 * NCELLS) {
    // full dispatch (1248 blocks): window-256 L2-tiled mapping (bijective)
    if (id < 1024) {
      const int a = id & 7, m = (id >> 3) & 7, h = (id >> 6) & 3, w = id >> 8;
      bx = m | ((a & 1) << 3);
      const int cb = (w << 4) | ((a >> 1) << 2) | h;  // 0..63
      ci = cb >> 1; by = cb & 1;
    } else {
      const int r = id - 1024;  // 0..223 tail: 14 cb x 16 bx
      bx = r & 15;
      const int cb = 64 + (r >> 4);  // 64..77
      ci = cb >> 1; by = cb & 1;
    }
  } else {
    // chunked fallback: round-2 generic mapping (bx pinned per XCD)
    const int xcd = id & 7;
    const int j = id >> 3;
    bx = xcd * 2 + (j & 1);
    by = (j >> 1) & 1;
    ci = j >> 2;
  }

  const unsigned short* Ag = Ebf + (size_t)bx * 256 * FD;
  const unsigned short* Bg = Wt + (size_t)ci * FD * FD + (size_t)by * 256 * FD;

  const int wave = t >> 6, lane = t & 63;
  const int wm = wave >> 2, wn = wave & 3;  // 2M x 4N wave grid
  const int lr = lane & 15, lq = lane >> 4;

  // staging: physical granule pg (row=pg>>3, g=pg&7); source uses g ^ (row&7)
  const int pg0 = t, pg1 = 512 + t;
  const int sr0 = pg0 >> 3, sg0 = pg0 & 7;
  const int sr1 = pg1 >> 3, sg1 = pg1 & 7;
  const int soff0 = sr0 * FD + ((sg0 ^ (sr0 & 7)) << 3);
  const int soff1 = sr1 * FD + ((sg1 ^ (sr1 & 7)) << 3);
  const int loff0 = pg0 * 8, loff1 = pg1 * 8;

  // read swizzle: frag rows always have row%8 == lr%8
  const int swz0 = (lq ^ (lr & 7)) << 3;        // k-slice 0 granule
  const int swz1 = ((4 + lq) ^ (lr & 7)) << 3;  // k-slice 1 granule

#define STAGE(OP, HALF, KT, GBASE)                                                \
  do {                                                                            \
    const int bi_ = (KT) & 1;             /* buffer from UNclamped kt */          \
    const int kt_ = (KT) < NT ? (KT) : (NT - 1); /* clamp src, keep count */      \
    const unsigned short* gb_ = (GBASE) + (size_t)(HALF) * (128 * FD) + kt_ * 64; \
    unsigned short* d_ = &lds[bi_][OP][HALF][0];                                  \
    async16(gb_ + soff0, d_ + loff0);                                             \
    async16(gb_ + soff1, d_ + loff1);                                             \
  } while (0)

  short8 a[8], b01[4], b23[4];
  f32x4 acc[8][4];
#pragma unroll
  for (int i = 0; i < 8; i++)
#pragma unroll
    for (int j2 = 0; j2 < 4; j2++) acc[i][j2] = (f32x4){0.f, 0.f, 0.f, 0.f};

#define LDA(BUF, MSET)                                                  \
  do {                                                                  \
    const unsigned short* p_ = &lds[BUF][0][wm][0];                     \
    _Pragma("unroll") for (int mi_ = 0; mi_ < 4; ++mi_) {               \
      const int row_ = (MSET) * 64 + mi_ * 16 + lr;                     \
      a[mi_ * 2 + 0] = *(const short8*)&p_[row_ * 64 + swz0];           \
      a[mi_ * 2 + 1] = *(const short8*)&p_[row_ * 64 + swz1];           \
    }                                                                   \
  } while (0)

#define LDB(BUF, NSET, DST)                                             \
  do {                                                                  \
    const unsigned short* p_ = &lds[BUF][1][wn >> 1][0];                \
    _Pragma("unroll") for (int ni_ = 0; ni_ < 2; ++ni_) {               \
      const int row_ = (wn & 1) * 64 + ((NSET) * 2 + ni_) * 16 + lr;    \
      (DST)[ni_ * 2 + 0] = *(const short8*)&p_[row_ * 64 + swz0];       \
      (DST)[ni_ * 2 + 1] = *(const short8*)&p_[row_ * 64 + swz1];       \
    }                                                                   \
  } while (0)

#define MMA(MSET, NSET, B)                                                               \
  do {                                                                                   \
    __builtin_amdgcn_s_setprio(1);                                                       \
    _Pragma("unroll") for (int mi_ = 0; mi_ < 4; ++mi_)                                  \
    _Pragma("unroll") for (int ni_ = 0; ni_ < 2; ++ni_)                                  \
    _Pragma("unroll") for (int s_ = 0; s_ < 2; ++s_)                                     \
      acc[(MSET) * 4 + mi_][(NSET) * 2 + ni_] = __builtin_amdgcn_mfma_f32_16x16x32_bf16( \
          a[mi_ * 2 + s_], (B)[ni_ * 2 + s_],                                            \
          acc[(MSET) * 4 + mi_][(NSET) * 2 + ni_], 0, 0, 0);                             \
    __builtin_amdgcn_s_setprio(0);                                                       \
  } while (0)

#define SYNC_LG()                                        \
  do {                                                   \
    __builtin_amdgcn_s_barrier();                        \
    asm volatile("s_waitcnt lgkmcnt(0)" ::: "memory");   \
  } while (0)

  // prologue: all 4 half-tiles of kt0 + B-lo,A-lo of kt1 (6 HTs = 12 loads)
  STAGE(1, 0, 0, Bg); STAGE(0, 0, 0, Ag); STAGE(1, 1, 0, Bg); STAGE(0, 1, 0, Ag);
  STAGE(1, 0, 1, Bg); STAGE(0, 0, 1, Ag);
  asm volatile("s_waitcnt vmcnt(4)" ::: "memory");  // kt0 fully landed
  __builtin_amdgcn_s_barrier();

  for (int it = 0; it < NT / 2; ++it) {
    const int k1 = 2 * it + 1, k2 = 2 * it + 2, k3 = 2 * it + 3;
    // ----- K-tile 2it from buf0 -----
    LDA(0, 0); LDB(0, 0, b01);
    STAGE(1, 1, k1, Bg);
    SYNC_LG(); MMA(0, 0, b01); __builtin_amdgcn_s_barrier();
    LDB(0, 1, b23);
    STAGE(0, 1, k1, Ag);
    SYNC_LG(); MMA(0, 1, b23); __builtin_amdgcn_s_barrier();
    LDA(0, 1);
    STAGE(1, 0, k2, Bg);
    SYNC_LG(); MMA(1, 1, b23); __builtin_amdgcn_s_barrier();
    STAGE(0, 0, k2, Ag);
    __builtin_amdgcn_s_barrier();
    MMA(1, 0, b01);
    asm volatile("s_waitcnt vmcnt(4)" ::: "memory");  // kt1 fully landed
    __builtin_amdgcn_s_barrier();
    // ----- K-tile 2it+1 from buf1 -----
    LDA(1, 0); LDB(1, 0, b01);
    STAGE(1, 1, k2, Bg);
    SYNC_LG(); MMA(0, 0, b01); __builtin_amdgcn_s_barrier();
    LDB(1, 1, b23);
    STAGE(0, 1, k2, Ag);
    SYNC_LG(); MMA(0, 1, b23); __builtin_amdgcn_s_barrier();
    LDA(1, 1);
    STAGE(1, 0, k3, Bg);
    SYNC_LG(); MMA(1, 1, b23); __builtin_amdgcn_s_barrier();
    STAGE(0, 0, k3, Ag);
    __builtin_amdgcn_s_barrier();
    MMA(1, 0, b01);
    asm volatile("s_waitcnt vmcnt(4)" ::: "memory");  // kt2 fully landed
    __builtin_amdgcn_s_barrier();
  }

  // ---- LDS-bounce epilogue ----
  // drain remaining staging DMA (final clamped refetches), LDS is then dead
  asm volatile("s_waitcnt vmcnt(0)" ::: "memory");
  __syncthreads();
  {
    unsigned short* Ut = &lds[0][0][0][0];  // [256][256] bf16 = 128KB
    const int mrow0w = wm * 128, ncol0w = wn * 64;
    // acc -> LDS, granule-XOR swizzle (r5-verified): conflict-free fragment
    // writes (4 lq-row-groups land on 4 disjoint 8-bank sets, 2 lanes/bank)
#pragma unroll
    for (int mi = 0; mi < 8; ++mi)
#pragma unroll
      for (int ni = 0; ni < 4; ++ni)
#pragma unroll
        for (int r = 0; r < 4; ++r) {
          const int row = mrow0w + mi * 16 + lq * 4 + r;
          const int col = ncol0w + ni * 16 + lr;
          Ut[row * 256 + (col ^ ((row & 12) << 2))] = f2bf(acc[mi][ni][r]);
        }
    __syncthreads();
    // coalesced out: 512 threads = 16 rows/pass x 32 lanes x 16B; 16 passes
    unsigned short* Up = U + (size_t)ci * NE * FD + (size_t)(bx * 256) * FD + by * 256;
    const int lrow = t >> 5;        // 0..15
    const int le = (t & 31) * 8;    // elem 0..248 (8-elem granules)
#pragma unroll
    for (int pass = 0; pass < 16; ++pass) {
      const int row = pass * 16 + lrow;
      const ushort8 vv = *(const ushort8*)&Ut[row * 256 + (le ^ ((row & 12) << 2))];
      *(ushort8*)&Up[(size_t)row * FD + le] = vv;
    }
  }
#undef STAGE
#undef LDA
#undef LDB
#undef MMA
#undef SYNC_LG
}

// ---- kernel 4: out[c,p] = sum_k U[ci,i0,k] * Ebf[i1,k] ----
// Transpose-butterfly reduce: 10 shuffles per 8-pair batch, identical tree.
__global__ __launch_bounds__(256) void dot_k(const unsigned short* __restrict__ U,
                                             const unsigned short* __restrict__ Ebf,
                                             const int* __restrict__ index,
                                             float* __restrict__ out,
                                             int c0) {
  const int ci = blockIdx.y;
  const int c = c0 + ci;
  const int wave = threadIdx.x >> 6, lane = threadIdx.x & 63;
  const unsigned short* Uc = U + (size_t)ci * NE * FD;
  const size_t cp = (size_t)c * NPAIRS;
  const int2* idx2 = (const int2*)index + cp;
  float* op = out + cp;
  const int pbase = (blockIdx.x * 4 + wave) * 32;

  const int b1 = lane & 1, b2 = (lane >> 1) & 1, b4 = (lane >> 2) & 1;

  for (int batch = 0; batch < 4; batch++) {
    const int pb = pbase + batch * 8;
    int2 id[8];
#pragma unroll
    for (int b = 0; b < 8; b++) id[b] = idx2[pb + b];
    uint4v uv[8], ev[8];
#pragma unroll
    for (int b = 0; b < 8; b++) {
      uv[b] = *(const uint4v*)(Uc + (size_t)id[b].x * FD + lane * 8);
      ev[b] = *(const uint4v*)(Ebf + (size_t)id[b].y * FD + lane * 8);
    }
    float v[8];
#pragma unroll
    for (int b = 0; b < 8; b++) {
      const ushort8 u = *(const ushort8*)&uv[b];
      const ushort8 e = *(const ushort8*)&ev[b];
      float s = 0.f;
#pragma unroll
      for (int q = 0; q < 8; q++) s += bf2f(u[q]) * bf2f(e[q]);
      v[b] = s;
    }
    // fold pair-index bit 0 into lane bit 0
    float w[4];
#pragma unroll
    for (int q = 0; q < 4; q++) {
      const float keep = b1 ? v[2 * q + 1] : v[2 * q];
      const float send = b1 ? v[2 * q] : v[2 * q + 1];
      w[q] = keep + __shfl_xor(send, 1, 64);
    }
    // bit 1
    float u2[2];
#pragma unroll
    for (int q = 0; q < 2; q++) {
      const float keep = b2 ? w[2 * q + 1] : w[2 * q];
      const float send = b2 ? w[2 * q] : w[2 * q + 1];
      u2[q] = keep + __shfl_xor(send, 2, 64);
    }
    // bit 2
    float f;
    {
      const float keep = b4 ? u2[1] : u2[0];
      const float send = b4 ? u2[0] : u2[1];
      f = keep + __shfl_xor(send, 4, 64);
    }
    // pure reduction across 8-lane groups; lane l now holds pair (l&7)
    f += __shfl_xor(f, 8, 64);
    f += __shfl_xor(f, 16, 64);
    f += __shfl_xor(f, 32, 64);
    if (lane < 8) op[pb + lane] = f;
  }
}

// ---- fallback (tiny workspace): direct fp32, slow but correct ----
__global__ __launch_bounds__(256) void naive_k(const float* __restrict__ emb,
                                               const int* __restrict__ index,
                                               const float* __restrict__ W,
                                               const float* __restrict__ wl,
                                               float* __restrict__ out) {
  __shared__ float bs[FD];
  __shared__ float red[256];
  const int c = blockIdx.y, p = blockIdx.x;
  const int i0 = index[((size_t)c * NPAIRS + p) * 2];
  const int i1 = index[((size_t)c * NPAIRS + p) * 2 + 1];
  const float* wlc = wl + (size_t)c * FD;
  for (int k = threadIdx.x; k < FD; k += 256) bs[k] = emb[(size_t)i1 * FD + k] * wlc[k];
  __syncthreads();
  float s = 0.f;
  for (int n = threadIdx.x; n < FD; n += 256) {
    const float* wr = W + (size_t)n * FD;
    float tacc = 0.f;
    for (int k = 0; k < FD; k++) tacc += wr[k] * bs[k];
    s += tacc * emb[(size_t)i0 * FD + n] * wlc[n];
  }
  red[threadIdx.x] = s;
  __syncthreads();
  for (int st = 128; st > 0; st >>= 1) {
    if (threadIdx.x < st) red[threadIdx.x] += red[threadIdx.x + st];
    __syncthreads();
  }
  if (threadIdx.x == 0) out[(size_t)c * NPAIRS + p] = red[0];
}

extern "C" void kernel_launch(void* const* d_in, const int* in_sizes, int n_in,
                              void* d_out, int out_size, void* d_ws, size_t ws_size,
                              hipStream_t stream) {
  const float* emb = (const float*)d_in[0];
  const int* index = (const int*)d_in[1];
  const float* Wg = (const float*)d_in[2];
  const float* wl = (const float*)d_in[3];
  float* out = (float*)d_out;

  const size_t ebytes = (size_t)NE * FD * 2;  // 4 MiB bf16 embedding
  const size_t wtcell = (size_t)FD * FD * 2;  // 0.5 MiB per-cell Wt
  const size_t ucell = (size_t)NE * FD * 2;   // 4 MiB per-cell U
  size_t avail = ws_size > ebytes ? ws_size - ebytes : 0;
  int G = (int)(avail / (wtcell + ucell));
  if (G > NCELLS) G = NCELLS;

  if (G < 1) {
    naive_k<<<dim3(NPAIRS, NCELLS), 256, 0, stream>>>(emb, index, Wg, wl, out);
    return;
  }

  unsigned short* Ebf = (unsigned short*)d_ws;
  unsigned short* Wt = (unsigned short*)((char*)d_ws + ebytes);
  unsigned short* U = (unsigned short*)((char*)d_ws + ebytes + (size_t)G * wtcell);

  if (G >= NCELLS) {
    // full path: merged init (conv 2048 blocks + prep 9984 blocks), one gemm,
    // one dot
    init_k<<<dim3(2048 + NCELLS * 256), 256, 0, stream>>>(emb, Ebf, Wg, wl, Wt);
    gemm_k<<<dim3(32 * NCELLS), 512, 0, stream>>>(Ebf, Wt, U);
    dot_k<<<dim3(NPAIRS / 128, NCELLS), 256, 0, stream>>>(U, Ebf, index, out, 0);
    return;
  }

  conv_e<<<dim3((NE * FD / 4) / 256), 256, 0, stream>>>(emb, Ebf);
  for (int c0 = 0; c0 < NCELLS; c0 += G) {
    int g = (NCELLS - c0 < G) ? (NCELLS - c0) : G;
    prep_w<<<dim3(FD / 32, FD / 32, g), 256, 0, stream>>>(Wg, wl, Wt, c0);
    gemm_k<<<dim3(32 * g), 512, 0, stream>>>(Ebf, Wt, U);
    dot_k<<<dim3(NPAIRS / 128, g), 256, 0, stream>>>(U, Ebf, index, out, c0);
  }
}

// Round 8
// 226.809 us; speedup vs baseline: 1.3483x; 1.0577x over previous
//
#include <hip/hip_runtime.h>
#include <stdint.h>

#define NE 4096
#define FD 512
#define NCELLS 39
#define NPAIRS 8192
#define NT (FD / 64)  // 8 K-tiles of BK=64

typedef __attribute__((ext_vector_type(8))) short short8;
typedef __attribute__((ext_vector_type(8))) unsigned short ushort8;
typedef __attribute__((ext_vector_type(4))) float f32x4;
typedef __attribute__((ext_vector_type(4))) unsigned int uint4v;

__device__ __forceinline__ unsigned short f2bf(float f) {
  union { float f; uint32_t u; } v; v.f = f;
  uint32_t u = v.u;
  return (unsigned short)((u + 0x7fffu + ((u >> 16) & 1u)) >> 16);  // RNE
}
__device__ __forceinline__ float bf2f(unsigned short b) {
  return __uint_as_float(((uint32_t)b) << 16);
}

__device__ __forceinline__ void async16(const void* g, void* l) {
  __builtin_amdgcn_global_load_lds((const __attribute__((address_space(1))) void*)g,
                                   (__attribute__((address_space(3))) void*)l, 16, 0, 0);
}

// ---- kernel 1 (merged): blocks [0,2048) convert embedding fp32->bf16;
//      blocks [2048,12032) build Wt[ci][k][n] = wl[c,n]*wl[c,k]*W[n,k] (bf16) ----
__global__ __launch_bounds__(256) void init_k(const float* __restrict__ E,
                                              unsigned short* __restrict__ Ebf,
                                              const float* __restrict__ W,
                                              const float* __restrict__ wl,
                                              unsigned short* __restrict__ Wt) {
  __shared__ float tile[32][33];
  const int bid = blockIdx.x;
  if (bid < 2048) {
    const int i = bid * 256 + threadIdx.x;
    const float4 v = ((const float4*)E)[i];
    ushort4 o;
    o.x = f2bf(v.x); o.y = f2bf(v.y); o.z = f2bf(v.z); o.w = f2bf(v.w);
    ((ushort4*)Ebf)[i] = o;
    return;
  }
  const int pid = bid - 2048;
  const int ci = pid >> 8;
  const int rem = pid & 255;
  const int tn = (rem & 15) * 32, tk = (rem >> 4) * 32;
  const int tx = threadIdx.x & 31, ty = threadIdx.x >> 5;
  const float* wlr = wl + (size_t)ci * FD;
#pragma unroll
  for (int i = 0; i < 4; i++) {
    int n = tn + ty + i * 8;
    tile[ty + i * 8][tx] = W[(size_t)n * FD + tk + tx] * wlr[n];
  }
  __syncthreads();
  unsigned short* dst = Wt + (size_t)ci * FD * FD;
#pragma unroll
  for (int i = 0; i < 4; i++) {
    int kout = tk + ty + i * 8;
    dst[(size_t)kout * FD + tn + tx] = f2bf(tile[tx][ty + i * 8] * wlr[kout]);
  }
}

// ---- standalone copies for the chunked fallback path ----
__global__ __launch_bounds__(256) void conv_e(const float* __restrict__ E,
                                              unsigned short* __restrict__ Ebf) {
  const int i = blockIdx.x * 256 + threadIdx.x;
  const float4 v = ((const float4*)E)[i];
  ushort4 o;
  o.x = f2bf(v.x); o.y = f2bf(v.y); o.z = f2bf(v.z); o.w = f2bf(v.w);
  ((ushort4*)Ebf)[i] = o;
}

__global__ __launch_bounds__(256) void prep_w(const float* __restrict__ W,
                                              const float* __restrict__ wl,
                                              unsigned short* __restrict__ Wt,
                                              int c0) {
  __shared__ float tile[32][33];
  const int ci = blockIdx.z;
  const int tn = blockIdx.x * 32, tk = blockIdx.y * 32;
  const int tx = threadIdx.x & 31, ty = threadIdx.x >> 5;
  const float* wlr = wl + (size_t)(c0 + ci) * FD;
#pragma unroll
  for (int i = 0; i < 4; i++) {
    int n = tn + ty + i * 8;
    tile[ty + i * 8][tx] = W[(size_t)n * FD + tk + tx] * wlr[n];
  }
  __syncthreads();
  unsigned short* dst = Wt + (size_t)ci * FD * FD;
#pragma unroll
  for (int i = 0; i < 4; i++) {
    int kout = tk + ty + i * 8;
    dst[(size_t)kout * FD + tn + tx] = f2bf(tile[tx][ty + i * 8] * wlr[kout]);
  }
}

// ---- kernel 3: U[ci][e][k] = sum_n Ebf[e,n] * Wt[ci][k][n]  (bf16 out) ----
// 256x256 8-phase template + window-256 L2-tiled mapping.  At its practical
// floor (~103us): bound by per-CU vector-memory staging rate (640MB @ ~6.2TB/s
// aggregate = m13 streaming ceiling); seven structural variants all land
// 102-118us.  Multi-cell accumulation is register-impossible (256 acc VGPRs),
// fp8 staging breaks the 2^-8 tolerance.
__global__ __launch_bounds__(512, 2) void gemm_k(const unsigned short* __restrict__ Ebf,
                                                 const unsigned short* __restrict__ Wt,
                                                 unsigned short* __restrict__ U) {
  __shared__ unsigned short lds[2][2][2][128 * 64];  // [buf][A=0/B=1][half][row*64+col]
  const int t = threadIdx.x;
  const int id = blockIdx.x;
  int bx, by, ci;
  if (gridDim.x == 32 * NCELLS) {
    // full dispatch (1248 blocks): window-256 L2-tiled mapping (bijective)
    if (id < 1024) {
      const int a = id & 7, m = (id >> 3) & 7, h = (id >> 6) & 3, w = id >> 8;
      bx = m | ((a & 1) << 3);
      const int cb = (w << 4) | ((a >> 1) << 2) | h;  // 0..63
      ci = cb >> 1; by = cb & 1;
    } else {
      const int r = id - 1024;  // 0..223 tail: 14 cb x 16 bx
      bx = r & 15;
      const int cb = 64 + (r >> 4);  // 64..77
      ci = cb >> 1; by = cb & 1;
    }
  } else {
    // chunked fallback: round-2 generic mapping (bx pinned per XCD)
    const int xcd = id & 7;
    const int j = id >> 3;
    bx = xcd * 2 + (j & 1);
    by = (j >> 1) & 1;
    ci = j >> 2;
  }

  const unsigned short* Ag = Ebf + (size_t)bx * 256 * FD;
  const unsigned short* Bg = Wt + (size_t)ci * FD * FD + (size_t)by * 256 * FD;

  const int wave = t >> 6, lane = t & 63;
  const int wm = wave >> 2, wn = wave & 3;  // 2M x 4N wave grid
  const int lr = lane & 15, lq = lane >> 4;

  // staging: physical granule pg (row=pg>>3, g=pg&7); source uses g ^ (row&7)
  const int pg0 = t, pg1 = 512 + t;
  const int sr0 = pg0 >> 3, sg0 = pg0 & 7;
  const int sr1 = pg1 >> 3, sg1 = pg1 & 7;
  const int soff0 = sr0 * FD + ((sg0 ^ (sr0 & 7)) << 3);
  const int soff1 = sr1 * FD + ((sg1 ^ (sr1 & 7)) << 3);
  const int loff0 = pg0 * 8, loff1 = pg1 * 8;

  // read swizzle: frag rows always have row%8 == lr%8
  const int swz0 = (lq ^ (lr & 7)) << 3;        // k-slice 0 granule
  const int swz1 = ((4 + lq) ^ (lr & 7)) << 3;  // k-slice 1 granule

#define STAGE(OP, HALF, KT, GBASE)                                                \
  do {                                                                            \
    const int bi_ = (KT) & 1;             /* buffer from UNclamped kt */          \
    const int kt_ = (KT) < NT ? (KT) : (NT - 1); /* clamp src, keep count */      \
    const unsigned short* gb_ = (GBASE) + (size_t)(HALF) * (128 * FD) + kt_ * 64; \
    unsigned short* d_ = &lds[bi_][OP][HALF][0];                                  \
    async16(gb_ + soff0, d_ + loff0);                                             \
    async16(gb_ + soff1, d_ + loff1);                                             \
  } while (0)

  short8 a[8], b01[4], b23[4];
  f32x4 acc[8][4];
#pragma unroll
  for (int i = 0; i < 8; i++)
#pragma unroll
    for (int j2 = 0; j2 < 4; j2++) acc[i][j2] = (f32x4){0.f, 0.f, 0.f, 0.f};

#define LDA(BUF, MSET)                                                  \
  do {                                                                  \
    const unsigned short* p_ = &lds[BUF][0][wm][0];                     \
    _Pragma("unroll") for (int mi_ = 0; mi_ < 4; ++mi_) {               \
      const int row_ = (MSET) * 64 + mi_ * 16 + lr;                     \
      a[mi_ * 2 + 0] = *(const short8*)&p_[row_ * 64 + swz0];           \
      a[mi_ * 2 + 1] = *(const short8*)&p_[row_ * 64 + swz1];           \
    }                                                                   \
  } while (0)

#define LDB(BUF, NSET, DST)                                             \
  do {                                                                  \
    const unsigned short* p_ = &lds[BUF][1][wn >> 1][0];                \
    _Pragma("unroll") for (int ni_ = 0; ni_ < 2; ++ni_) {               \
      const int row_ = (wn & 1) * 64 + ((NSET) * 2 + ni_) * 16 + lr;    \
      (DST)[ni_ * 2 + 0] = *(const short8*)&p_[row_ * 64 + swz0];       \
      (DST)[ni_ * 2 + 1] = *(const short8*)&p_[row_ * 64 + swz1];       \
    }                                                                   \
  } while (0)

#define MMA(MSET, NSET, B)                                                               \
  do {                                                                                   \
    __builtin_amdgcn_s_setprio(1);                                                       \
    _Pragma("unroll") for (int mi_ = 0; mi_ < 4; ++mi_)                                  \
    _Pragma("unroll") for (int ni_ = 0; ni_ < 2; ++ni_)                                  \
    _Pragma("unroll") for (int s_ = 0; s_ < 2; ++s_)                                     \
      acc[(MSET) * 4 + mi_][(NSET) * 2 + ni_] = __builtin_amdgcn_mfma_f32_16x16x32_bf16( \
          a[mi_ * 2 + s_], (B)[ni_ * 2 + s_],                                            \
          acc[(MSET) * 4 + mi_][(NSET) * 2 + ni_], 0, 0, 0);                             \
    __builtin_amdgcn_s_setprio(0);                                                       \
  } while (0)

#define SYNC_LG()                                        \
  do {                                                   \
    __builtin_amdgcn_s_barrier();                        \
    asm volatile("s_waitcnt lgkmcnt(0)" ::: "memory");   \
  } while (0)

  // prologue: all 4 half-tiles of kt0 + B-lo,A-lo of kt1 (6 HTs = 12 loads)
  STAGE(1, 0, 0, Bg); STAGE(0, 0, 0, Ag); STAGE(1, 1, 0, Bg); STAGE(0, 1, 0, Ag);
  STAGE(1, 0, 1, Bg); STAGE(0, 0, 1, Ag);
  asm volatile("s_waitcnt vmcnt(4)" ::: "memory");  // kt0 fully landed
  __builtin_amdgcn_s_barrier();

  for (int it = 0; it < NT / 2; ++it) {
    const int k1 = 2 * it + 1, k2 = 2 * it + 2, k3 = 2 * it + 3;
    // ----- K-tile 2it from buf0 -----
    LDA(0, 0); LDB(0, 0, b01);
    STAGE(1, 1, k1, Bg);
    SYNC_LG(); MMA(0, 0, b01); __builtin_amdgcn_s_barrier();
    LDB(0, 1, b23);
    STAGE(0, 1, k1, Ag);
    SYNC_LG(); MMA(0, 1, b23); __builtin_amdgcn_s_barrier();
    LDA(0, 1);
    STAGE(1, 0, k2, Bg);
    SYNC_LG(); MMA(1, 1, b23); __builtin_amdgcn_s_barrier();
    STAGE(0, 0, k2, Ag);
    __builtin_amdgcn_s_barrier();
    MMA(1, 0, b01);
    asm volatile("s_waitcnt vmcnt(4)" ::: "memory");  // kt1 fully landed
    __builtin_amdgcn_s_barrier();
    // ----- K-tile 2it+1 from buf1 -----
    LDA(1, 0); LDB(1, 0, b01);
    STAGE(1, 1, k2, Bg);
    SYNC_LG(); MMA(0, 0, b01); __builtin_amdgcn_s_barrier();
    LDB(1, 1, b23);
    STAGE(0, 1, k2, Ag);
    SYNC_LG(); MMA(0, 1, b23); __builtin_amdgcn_s_barrier();
    LDA(1, 1);
    STAGE(1, 0, k3, Bg);
    SYNC_LG(); MMA(1, 1, b23); __builtin_amdgcn_s_barrier();
    STAGE(0, 0, k3, Ag);
    __builtin_amdgcn_s_barrier();
    MMA(1, 0, b01);
    asm volatile("s_waitcnt vmcnt(4)" ::: "memory");  // kt2 fully landed
    __builtin_amdgcn_s_barrier();
  }

  // epilogue: direct store (r7 A/B showed LDS-bounce is not better)
  unsigned short* Up = U + (size_t)ci * NE * FD;
  const int mrow0 = bx * 256 + wm * 128;
  const int ncol0 = by * 256 + wn * 64;
#pragma unroll
  for (int mi = 0; mi < 8; ++mi) {
    const int mbase = mrow0 + mi * 16 + lq * 4;
#pragma unroll
    for (int ni = 0; ni < 4; ++ni) {
      const int n = ncol0 + ni * 16 + lr;
#pragma unroll
      for (int r = 0; r < 4; ++r)
        Up[(size_t)(mbase + r) * FD + n] = f2bf(acc[mi][ni][r]);
    }
  }
#undef STAGE
#undef LDA
#undef LDB
#undef MMA
#undef SYNC_LG
}

// ---- kernel 4 (full path): cell->XCD pinned dot ----
// All 64 pair-blocks of cell c run on XCD c%8, so U[c] (4MB) becomes
// L2-resident after first touch: U reads move from L3 (~8TB/s, the measured
// dot bottleneck) to per-XCD L2.  Body identical to dot_k.
__global__ __launch_bounds__(256) void dot_p(const unsigned short* __restrict__ U,
                                             const unsigned short* __restrict__ Ebf,
                                             const int* __restrict__ index,
                                             float* __restrict__ out) {
  const int id = blockIdx.x;
  const int xcd = id & 7;
  const int j = id >> 3;            // 0..319
  const int ci = xcd + 8 * (j >> 6);
  if (ci >= NCELLS) return;
  const int pairblock = j & 63;

  const int wave = threadIdx.x >> 6, lane = threadIdx.x & 63;
  const unsigned short* Uc = U + (size_t)ci * NE * FD;
  const size_t cp = (size_t)ci * NPAIRS;
  const int2* idx2 = (const int2*)index + cp;
  float* op = out + cp;
  const int pbase = (pairblock * 4 + wave) * 32;

  const int b1 = lane & 1, b2 = (lane >> 1) & 1, b4 = (lane >> 2) & 1;

  for (int batch = 0; batch < 4; batch++) {
    const int pb = pbase + batch * 8;
    int2 id8[8];
#pragma unroll
    for (int b = 0; b < 8; b++) id8[b] = idx2[pb + b];
    uint4v uv[8], ev[8];
#pragma unroll
    for (int b = 0; b < 8; b++) {
      uv[b] = *(const uint4v*)(Uc + (size_t)id8[b].x * FD + lane * 8);
      ev[b] = *(const uint4v*)(Ebf + (size_t)id8[b].y * FD + lane * 8);
    }
    float v[8];
#pragma unroll
    for (int b = 0; b < 8; b++) {
      const ushort8 u = *(const ushort8*)&uv[b];
      const ushort8 e = *(const ushort8*)&ev[b];
      float s = 0.f;
#pragma unroll
      for (int q = 0; q < 8; q++) s += bf2f(u[q]) * bf2f(e[q]);
      v[b] = s;
    }
    float w[4];
#pragma unroll
    for (int q = 0; q < 4; q++) {
      const float keep = b1 ? v[2 * q + 1] : v[2 * q];
      const float send = b1 ? v[2 * q] : v[2 * q + 1];
      w[q] = keep + __shfl_xor(send, 1, 64);
    }
    float u2[2];
#pragma unroll
    for (int q = 0; q < 2; q++) {
      const float keep = b2 ? w[2 * q + 1] : w[2 * q];
      const float send = b2 ? w[2 * q] : w[2 * q + 1];
      u2[q] = keep + __shfl_xor(send, 2, 64);
    }
    float f;
    {
      const float keep = b4 ? u2[1] : u2[0];
      const float send = b4 ? u2[0] : u2[1];
      f = keep + __shfl_xor(send, 4, 64);
    }
    f += __shfl_xor(f, 8, 64);
    f += __shfl_xor(f, 16, 64);
    f += __shfl_xor(f, 32, 64);
    if (lane < 8) op[pb + lane] = f;
  }
}

// ---- kernel 4b (chunked fallback): original 2-D mapping ----
__global__ __launch_bounds__(256) void dot_k(const unsigned short* __restrict__ U,
                                             const unsigned short* __restrict__ Ebf,
                                             const int* __restrict__ index,
                                             float* __restrict__ out,
                                             int c0) {
  const int ci = blockIdx.y;
  const int c = c0 + ci;
  const int wave = threadIdx.x >> 6, lane = threadIdx.x & 63;
  const unsigned short* Uc = U + (size_t)ci * NE * FD;
  const size_t cp = (size_t)c * NPAIRS;
  const int2* idx2 = (const int2*)index + cp;
  float* op = out + cp;
  const int pbase = (blockIdx.x * 4 + wave) * 32;

  const int b1 = lane & 1, b2 = (lane >> 1) & 1, b4 = (lane >> 2) & 1;

  for (int batch = 0; batch < 4; batch++) {
    const int pb = pbase + batch * 8;
    int2 id[8];
#pragma unroll
    for (int b = 0; b < 8; b++) id[b] = idx2[pb + b];
    uint4v uv[8], ev[8];
#pragma unroll
    for (int b = 0; b < 8; b++) {
      uv[b] = *(const uint4v*)(Uc + (size_t)id[b].x * FD + lane * 8);
      ev[b] = *(const uint4v*)(Ebf + (size_t)id[b].y * FD + lane * 8);
    }
    float v[8];
#pragma unroll
    for (int b = 0; b < 8; b++) {
      const ushort8 u = *(const ushort8*)&uv[b];
      const ushort8 e = *(const ushort8*)&ev[b];
      float s = 0.f;
#pragma unroll
      for (int q = 0; q < 8; q++) s += bf2f(u[q]) * bf2f(e[q]);
      v[b] = s;
    }
    float w[4];
#pragma unroll
    for (int q = 0; q < 4; q++) {
      const float keep = b1 ? v[2 * q + 1] : v[2 * q];
      const float send = b1 ? v[2 * q] : v[2 * q + 1];
      w[q] = keep + __shfl_xor(send, 1, 64);
    }
    float u2[2];
#pragma unroll
    for (int q = 0; q < 2; q++) {
      const float keep = b2 ? w[2 * q + 1] : w[2 * q];
      const float send = b2 ? w[2 * q] : w[2 * q + 1];
      u2[q] = keep + __shfl_xor(send, 2, 64);
    }
    float f;
    {
      const float keep = b4 ? u2[1] : u2[0];
      const float send = b4 ? u2[0] : u2[1];
      f = keep + __shfl_xor(send, 4, 64);
    }
    f += __shfl_xor(f, 8, 64);
    f += __shfl_xor(f, 16, 64);
    f += __shfl_xor(f, 32, 64);
    if (lane < 8) op[pb + lane] = f;
  }
}

// ---- fallback (tiny workspace): direct fp32, slow but correct ----
__global__ __launch_bounds__(256) void naive_k(const float* __restrict__ emb,
                                               const int* __restrict__ index,
                                               const float* __restrict__ W,
                                               const float* __restrict__ wl,
                                               float* __restrict__ out) {
  __shared__ float bs[FD];
  __shared__ float red[256];
  const int c = blockIdx.y, p = blockIdx.x;
  const int i0 = index[((size_t)c * NPAIRS + p) * 2];
  const int i1 = index[((size_t)c * NPAIRS + p) * 2 + 1];
  const float* wlc = wl + (size_t)c * FD;
  for (int k = threadIdx.x; k < FD; k += 256) bs[k] = emb[(size_t)i1 * FD + k] * wlc[k];
  __syncthreads();
  float s = 0.f;
  for (int n = threadIdx.x; n < FD; n += 256) {
    const float* wr = W + (size_t)n * FD;
    float tacc = 0.f;
    for (int k = 0; k < FD; k++) tacc += wr[k] * bs[k];
    s += tacc * emb[(size_t)i0 * FD + n] * wlc[n];
  }
  red[threadIdx.x] = s;
  __syncthreads();
  for (int st = 128; st > 0; st >>= 1) {
    if (threadIdx.x < st) red[threadIdx.x] += red[threadIdx.x + st];
    __syncthreads();
  }
  if (threadIdx.x == 0) out[(size_t)c * NPAIRS + p] = red[0];
}

extern "C" void kernel_launch(void* const* d_in, const int* in_sizes, int n_in,
                              void* d_out, int out_size, void* d_ws, size_t ws_size,
                              hipStream_t stream) {
  const float* emb = (const float*)d_in[0];
  const int* index = (const int*)d_in[1];
  const float* Wg = (const float*)d_in[2];
  const float* wl = (const float*)d_in[3];
  float* out = (float*)d_out;

  const size_t ebytes = (size_t)NE * FD * 2;  // 4 MiB bf16 embedding
  const size_t wtcell = (size_t)FD * FD * 2;  // 0.5 MiB per-cell Wt
  const size_t ucell = (size_t)NE * FD * 2;   // 4 MiB per-cell U
  size_t avail = ws_size > ebytes ? ws_size - ebytes : 0;
  int G = (int)(avail / (wtcell + ucell));
  if (G > NCELLS) G = NCELLS;

  if (G < 1) {
    naive_k<<<dim3(NPAIRS, NCELLS), 256, 0, stream>>>(emb, index, Wg, wl, out);
    return;
  }

  unsigned short* Ebf = (unsigned short*)d_ws;
  unsigned short* Wt = (unsigned short*)((char*)d_ws + ebytes);
  unsigned short* U = (unsigned short*)((char*)d_ws + ebytes + (size_t)G * wtcell);

  if (G >= NCELLS) {
    // full path: merged init, one gemm (window-mapped), cell->XCD pinned dot
    init_k<<<dim3(2048 + NCELLS * 256), 256, 0, stream>>>(emb, Ebf, Wg, wl, Wt);
    gemm_k<<<dim3(32 * NCELLS), 512, 0, stream>>>(Ebf, Wt, U);
    dot_p<<<dim3(8 * 320), 256, 0, stream>>>(U, Ebf, index, out);
    return;
  }

  conv_e<<<dim3((NE * FD / 4) / 256), 256, 0, stream>>>(emb, Ebf);
  for (int c0 = 0; c0 < NCELLS; c0 += G) {
    int g = (NCELLS - c0 < G) ? (NCELLS - c0) : G;
    prep_w<<<dim3(FD / 32, FD / 32, g), 256, 0, stream>>>(Wg, wl, Wt, c0);
    gemm_k<<<dim3(32 * g), 512, 0, stream>>>(Ebf, Wt, U);
    dot_k<<<dim3(NPAIRS / 128, g), 256, 0, stream>>>(U, Ebf, index, out, c0);
  }
}

// Round 9
// 219.923 us; speedup vs baseline: 1.3905x; 1.0313x over previous
//
#include <hip/hip_runtime.h>
#include <stdint.h>

#define NE 4096
#define FD 512
#define NCELLS 39
#define NPAIRS 8192
#define NT (FD / 64)  // 8 K-tiles of BK=64

typedef __attribute__((ext_vector_type(8))) short short8;
typedef __attribute__((ext_vector_type(8))) unsigned short ushort8;
typedef __attribute__((ext_vector_type(4))) float f32x4;
typedef __attribute__((ext_vector_type(4))) unsigned int uint4v;

__device__ __forceinline__ unsigned short f2bf(float f) {
  union { float f; uint32_t u; } v; v.f = f;
  uint32_t u = v.u;
  return (unsigned short)((u + 0x7fffu + ((u >> 16) & 1u)) >> 16);  // RNE
}
__device__ __forceinline__ float bf2f(unsigned short b) {
  return __uint_as_float(((uint32_t)b) << 16);
}

__device__ __forceinline__ void async16(const void* g, void* l) {
  __builtin_amdgcn_global_load_lds((const __attribute__((address_space(1))) void*)g,
                                   (__attribute__((address_space(3))) void*)l, 16, 0, 0);
}

// ---- kernel 1 (merged): blocks [0,2048) convert embedding fp32->bf16;
//      blocks [2048,12032) build Wt[ci][k][n] = wl[c,n]*wl[c,k]*W[n,k] (bf16) ----
__global__ __launch_bounds__(256) void init_k(const float* __restrict__ E,
                                              unsigned short* __restrict__ Ebf,
                                              const float* __restrict__ W,
                                              const float* __restrict__ wl,
                                              unsigned short* __restrict__ Wt) {
  __shared__ float tile[32][33];
  const int bid = blockIdx.x;
  if (bid < 2048) {
    const int i = bid * 256 + threadIdx.x;
    const float4 v = ((const float4*)E)[i];
    ushort4 o;
    o.x = f2bf(v.x); o.y = f2bf(v.y); o.z = f2bf(v.z); o.w = f2bf(v.w);
    ((ushort4*)Ebf)[i] = o;
    return;
  }
  const int pid = bid - 2048;
  const int ci = pid >> 8;
  const int rem = pid & 255;
  const int tn = (rem & 15) * 32, tk = (rem >> 4) * 32;
  const int tx = threadIdx.x & 31, ty = threadIdx.x >> 5;
  const float* wlr = wl + (size_t)ci * FD;
#pragma unroll
  for (int i = 0; i < 4; i++) {
    int n = tn + ty + i * 8;
    tile[ty + i * 8][tx] = W[(size_t)n * FD + tk + tx] * wlr[n];
  }
  __syncthreads();
  unsigned short* dst = Wt + (size_t)ci * FD * FD;
#pragma unroll
  for (int i = 0; i < 4; i++) {
    int kout = tk + ty + i * 8;
    dst[(size_t)kout * FD + tn + tx] = f2bf(tile[tx][ty + i * 8] * wlr[kout]);
  }
}

// ---- standalone copies for the chunked fallback path ----
__global__ __launch_bounds__(256) void conv_e(const float* __restrict__ E,
                                              unsigned short* __restrict__ Ebf) {
  const int i = blockIdx.x * 256 + threadIdx.x;
  const float4 v = ((const float4*)E)[i];
  ushort4 o;
  o.x = f2bf(v.x); o.y = f2bf(v.y); o.z = f2bf(v.z); o.w = f2bf(v.w);
  ((ushort4*)Ebf)[i] = o;
}

__global__ __launch_bounds__(256) void prep_w(const float* __restrict__ W,
                                              const float* __restrict__ wl,
                                              unsigned short* __restrict__ Wt,
                                              int c0) {
  __shared__ float tile[32][33];
  const int ci = blockIdx.z;
  const int tn = blockIdx.x * 32, tk = blockIdx.y * 32;
  const int tx = threadIdx.x & 31, ty = threadIdx.x >> 5;
  const float* wlr = wl + (size_t)(c0 + ci) * FD;
#pragma unroll
  for (int i = 0; i < 4; i++) {
    int n = tn + ty + i * 8;
    tile[ty + i * 8][tx] = W[(size_t)n * FD + tk + tx] * wlr[n];
  }
  __syncthreads();
  unsigned short* dst = Wt + (size_t)ci * FD * FD;
#pragma unroll
  for (int i = 0; i < 4; i++) {
    int kout = tk + ty + i * 8;
    dst[(size_t)kout * FD + tn + tx] = f2bf(tile[tx][ty + i * 8] * wlr[kout]);
  }
}

// ---- kernel 3: U[ci][e][k] = sum_n Ebf[e,n] * Wt[ci][k][n]  (bf16 out) ----
// 256x256 8-phase template + window-256 L2-tiled mapping.  At its practical
// floor (~103us): staging-latency bound (in-flight DMA capped by the 2-buffer
// schedule); seven structural variants all land 102-118us.
__global__ __launch_bounds__(512, 2) void gemm_k(const unsigned short* __restrict__ Ebf,
                                                 const unsigned short* __restrict__ Wt,
                                                 unsigned short* __restrict__ U) {
  __shared__ unsigned short lds[2][2][2][128 * 64];  // [buf][A=0/B=1][half][row*64+col]
  const int t = threadIdx.x;
  const int id = blockIdx.x;
  int bx, by, ci;
  if (gridDim.x == 32 * NCELLS) {
    // full dispatch (1248 blocks): window-256 L2-tiled mapping (bijective)
    if (id < 1024) {
      const int a = id & 7, m = (id >> 3) & 7, h = (id >> 6) & 3, w = id >> 8;
      bx = m | ((a & 1) << 3);
      const int cb = (w << 4) | ((a >> 1) << 2) | h;  // 0..63
      ci = cb >> 1; by = cb & 1;
    } else {
      const int r = id - 1024;  // 0..223 tail: 14 cb x 16 bx
      bx = r & 15;
      const int cb = 64 + (r >> 4);  // 64..77
      ci = cb >> 1; by = cb & 1;
    }
  } else {
    // chunked fallback: round-2 generic mapping (bx pinned per XCD)
    const int xcd = id & 7;
    const int j = id >> 3;
    bx = xcd * 2 + (j & 1);
    by = (j >> 1) & 1;
    ci = j >> 2;
  }

  const unsigned short* Ag = Ebf + (size_t)bx * 256 * FD;
  const unsigned short* Bg = Wt + (size_t)ci * FD * FD + (size_t)by * 256 * FD;

  const int wave = t >> 6, lane = t & 63;
  const int wm = wave >> 2, wn = wave & 3;  // 2M x 4N wave grid
  const int lr = lane & 15, lq = lane >> 4;

  // staging: physical granule pg (row=pg>>3, g=pg&7); source uses g ^ (row&7)
  const int pg0 = t, pg1 = 512 + t;
  const int sr0 = pg0 >> 3, sg0 = pg0 & 7;
  const int sr1 = pg1 >> 3, sg1 = pg1 & 7;
  const int soff0 = sr0 * FD + ((sg0 ^ (sr0 & 7)) << 3);
  const int soff1 = sr1 * FD + ((sg1 ^ (sr1 & 7)) << 3);
  const int loff0 = pg0 * 8, loff1 = pg1 * 8;

  // read swizzle: frag rows always have row%8 == lr%8
  const int swz0 = (lq ^ (lr & 7)) << 3;        // k-slice 0 granule
  const int swz1 = ((4 + lq) ^ (lr & 7)) << 3;  // k-slice 1 granule

#define STAGE(OP, HALF, KT, GBASE)                                                \
  do {                                                                            \
    const int bi_ = (KT) & 1;             /* buffer from UNclamped kt */          \
    const int kt_ = (KT) < NT ? (KT) : (NT - 1); /* clamp src, keep count */      \
    const unsigned short* gb_ = (GBASE) + (size_t)(HALF) * (128 * FD) + kt_ * 64; \
    unsigned short* d_ = &lds[bi_][OP][HALF][0];                                  \
    async16(gb_ + soff0, d_ + loff0);                                             \
    async16(gb_ + soff1, d_ + loff1);                                             \
  } while (0)

  short8 a[8], b01[4], b23[4];
  f32x4 acc[8][4];
#pragma unroll
  for (int i = 0; i < 8; i++)
#pragma unroll
    for (int j2 = 0; j2 < 4; j2++) acc[i][j2] = (f32x4){0.f, 0.f, 0.f, 0.f};

#define LDA(BUF, MSET)                                                  \
  do {                                                                  \
    const unsigned short* p_ = &lds[BUF][0][wm][0];                     \
    _Pragma("unroll") for (int mi_ = 0; mi_ < 4; ++mi_) {               \
      const int row_ = (MSET) * 64 + mi_ * 16 + lr;                     \
      a[mi_ * 2 + 0] = *(const short8*)&p_[row_ * 64 + swz0];           \
      a[mi_ * 2 + 1] = *(const short8*)&p_[row_ * 64 + swz1];           \
    }                                                                   \
  } while (0)

#define LDB(BUF, NSET, DST)                                             \
  do {                                                                  \
    const unsigned short* p_ = &lds[BUF][1][wn >> 1][0];                \
    _Pragma("unroll") for (int ni_ = 0; ni_ < 2; ++ni_) {               \
      const int row_ = (wn & 1) * 64 + ((NSET) * 2 + ni_) * 16 + lr;    \
      (DST)[ni_ * 2 + 0] = *(const short8*)&p_[row_ * 64 + swz0];       \
      (DST)[ni_ * 2 + 1] = *(const short8*)&p_[row_ * 64 + swz1];       \
    }                                                                   \
  } while (0)

#define MMA(MSET, NSET, B)                                                               \
  do {                                                                                   \
    __builtin_amdgcn_s_setprio(1);                                                       \
    _Pragma("unroll") for (int mi_ = 0; mi_ < 4; ++mi_)                                  \
    _Pragma("unroll") for (int ni_ = 0; ni_ < 2; ++ni_)                                  \
    _Pragma("unroll") for (int s_ = 0; s_ < 2; ++s_)                                     \
      acc[(MSET) * 4 + mi_][(NSET) * 2 + ni_] = __builtin_amdgcn_mfma_f32_16x16x32_bf16( \
          a[mi_ * 2 + s_], (B)[ni_ * 2 + s_],                                            \
          acc[(MSET) * 4 + mi_][(NSET) * 2 + ni_], 0, 0, 0);                             \
    __builtin_amdgcn_s_setprio(0);                                                       \
  } while (0)

#define SYNC_LG()                                        \
  do {                                                   \
    __builtin_amdgcn_s_barrier();                        \
    asm volatile("s_waitcnt lgkmcnt(0)" ::: "memory");   \
  } while (0)

  // prologue: all 4 half-tiles of kt0 + B-lo,A-lo of kt1 (6 HTs = 12 loads)
  STAGE(1, 0, 0, Bg); STAGE(0, 0, 0, Ag); STAGE(1, 1, 0, Bg); STAGE(0, 1, 0, Ag);
  STAGE(1, 0, 1, Bg); STAGE(0, 0, 1, Ag);
  asm volatile("s_waitcnt vmcnt(4)" ::: "memory");  // kt0 fully landed
  __builtin_amdgcn_s_barrier();

  for (int it = 0; it < NT / 2; ++it) {
    const int k1 = 2 * it + 1, k2 = 2 * it + 2, k3 = 2 * it + 3;
    // ----- K-tile 2it from buf0 -----
    LDA(0, 0); LDB(0, 0, b01);
    STAGE(1, 1, k1, Bg);
    SYNC_LG(); MMA(0, 0, b01); __builtin_amdgcn_s_barrier();
    LDB(0, 1, b23);
    STAGE(0, 1, k1, Ag);
    SYNC_LG(); MMA(0, 1, b23); __builtin_amdgcn_s_barrier();
    LDA(0, 1);
    STAGE(1, 0, k2, Bg);
    SYNC_LG(); MMA(1, 1, b23); __builtin_amdgcn_s_barrier();
    STAGE(0, 0, k2, Ag);
    __builtin_amdgcn_s_barrier();
    MMA(1, 0, b01);
    asm volatile("s_waitcnt vmcnt(4)" ::: "memory");  // kt1 fully landed
    __builtin_amdgcn_s_barrier();
    // ----- K-tile 2it+1 from buf1 -----
    LDA(1, 0); LDB(1, 0, b01);
    STAGE(1, 1, k2, Bg);
    SYNC_LG(); MMA(0, 0, b01); __builtin_amdgcn_s_barrier();
    LDB(1, 1, b23);
    STAGE(0, 1, k2, Ag);
    SYNC_LG(); MMA(0, 1, b23); __builtin_amdgcn_s_barrier();
    LDA(1, 1);
    STAGE(1, 0, k3, Bg);
    SYNC_LG(); MMA(1, 1, b23); __builtin_amdgcn_s_barrier();
    STAGE(0, 0, k3, Ag);
    __builtin_amdgcn_s_barrier();
    MMA(1, 0, b01);
    asm volatile("s_waitcnt vmcnt(4)" ::: "memory");  // kt2 fully landed
    __builtin_amdgcn_s_barrier();
  }

  // epilogue: direct store
  unsigned short* Up = U + (size_t)ci * NE * FD;
  const int mrow0 = bx * 256 + wm * 128;
  const int ncol0 = by * 256 + wn * 64;
#pragma unroll
  for (int mi = 0; mi < 8; ++mi) {
    const int mbase = mrow0 + mi * 16 + lq * 4;
#pragma unroll
    for (int ni = 0; ni < 4; ++ni) {
      const int n = ncol0 + ni * 16 + lr;
#pragma unroll
      for (int r = 0; r < 4; ++r)
        Up[(size_t)(mbase + r) * FD + n] = f2bf(acc[mi][ni][r]);
    }
  }
#undef STAGE
#undef LDA
#undef LDB
#undef MMA
#undef SYNC_LG
}

// ---- kernel 4 (full path): cell->XCD pinned dot, TWO-PASS k-split ----
// Pass h reads only U[ci][:,h*256..] (2MB) + Ebf[:,h*256..] (2MB) = 4MB =
// one XCD L2 (was 8MB -> U/E evicted each other; measured ~9.4TB/s).  32
// lanes cover one 512B half-row (16B/lane, same load size/count as before);
// lane bit 5 selects one of 2 pair-subgroups -> 16 pairs/batch.  Butterfly:
// fold pair bits into lane bits 0-2 (xor 1/2/4), reduce lane bits 3-4 only
// (xor 8/16); bit 5 never shuffled.  h=0 held in registers, h=1 adds+writes.
__global__ __launch_bounds__(256) void dot_p(const unsigned short* __restrict__ U,
                                             const unsigned short* __restrict__ Ebf,
                                             const int* __restrict__ index,
                                             float* __restrict__ out) {
  const int id = blockIdx.x;
  const int xcd = id & 7;
  const int j = id >> 3;            // 0..319
  const int ci = xcd + 8 * (j >> 6);
  if (ci >= NCELLS) return;
  const int pairblock = j & 63;

  const int wave = threadIdx.x >> 6, lane = threadIdx.x & 63;
  const int l5 = lane & 31, psub = lane >> 5;
  const unsigned short* Uc = U + (size_t)ci * NE * FD;
  const size_t cp = (size_t)ci * NPAIRS;
  const int2* idx2 = (const int2*)index + cp;
  float* op = out + cp;
  const int pbase = (pairblock * 4 + wave) * 32;

  const int b1 = lane & 1, b2 = (lane >> 1) & 1, b4 = (lane >> 2) & 1;

  float accb[2];
#pragma unroll
  for (int h = 0; h < 2; ++h) {
    const int off = h * 256;
#pragma unroll
    for (int batch = 0; batch < 2; ++batch) {
      const int pb = pbase + batch * 16;
      int2 id8[8];
#pragma unroll
      for (int b = 0; b < 8; b++) id8[b] = idx2[pb + 2 * b + psub];
      uint4v uv[8], ev[8];
#pragma unroll
      for (int b = 0; b < 8; b++) {
        uv[b] = *(const uint4v*)(Uc + (size_t)id8[b].x * FD + off + l5 * 8);
        ev[b] = *(const uint4v*)(Ebf + (size_t)id8[b].y * FD + off + l5 * 8);
      }
      float v[8];
#pragma unroll
      for (int b = 0; b < 8; b++) {
        const ushort8 u = *(const ushort8*)&uv[b];
        const ushort8 e = *(const ushort8*)&ev[b];
        float s = 0.f;
#pragma unroll
        for (int q = 0; q < 8; q++) s += bf2f(u[q]) * bf2f(e[q]);
        v[b] = s;
      }
      // fold pair-register bits into lane bits 0-2
      float w[4];
#pragma unroll
      for (int q = 0; q < 4; q++) {
        const float keep = b1 ? v[2 * q + 1] : v[2 * q];
        const float send = b1 ? v[2 * q] : v[2 * q + 1];
        w[q] = keep + __shfl_xor(send, 1, 64);
      }
      float u2[2];
#pragma unroll
      for (int q = 0; q < 2; q++) {
        const float keep = b2 ? w[2 * q + 1] : w[2 * q];
        const float send = b2 ? w[2 * q] : w[2 * q + 1];
        u2[q] = keep + __shfl_xor(send, 2, 64);
      }
      float f;
      {
        const float keep = b4 ? u2[1] : u2[0];
        const float send = b4 ? u2[0] : u2[1];
        f = keep + __shfl_xor(send, 4, 64);
      }
      // reduce remaining lane bits 3,4 (bit 5 = pair-subgroup, untouched)
      f += __shfl_xor(f, 8, 64);
      f += __shfl_xor(f, 16, 64);
      if (h == 0) {
        accb[batch] = f;
      } else if ((lane & 24) == 0) {
        op[pb + ((lane & 7) * 2 + psub)] = accb[batch] + f;
      }
    }
  }
}

// ---- kernel 4b (chunked fallback): original 2-D mapping ----
__global__ __launch_bounds__(256) void dot_k(const unsigned short* __restrict__ U,
                                             const unsigned short* __restrict__ Ebf,
                                             const int* __restrict__ index,
                                             float* __restrict__ out,
                                             int c0) {
  const int ci = blockIdx.y;
  const int c = c0 + ci;
  const int wave = threadIdx.x >> 6, lane = threadIdx.x & 63;
  const unsigned short* Uc = U + (size_t)ci * NE * FD;
  const size_t cp = (size_t)c * NPAIRS;
  const int2* idx2 = (const int2*)index + cp;
  float* op = out + cp;
  const int pbase = (blockIdx.x * 4 + wave) * 32;

  const int b1 = lane & 1, b2 = (lane >> 1) & 1, b4 = (lane >> 2) & 1;

  for (int batch = 0; batch < 4; batch++) {
    const int pb = pbase + batch * 8;
    int2 id[8];
#pragma unroll
    for (int b = 0; b < 8; b++) id[b] = idx2[pb + b];
    uint4v uv[8], ev[8];
#pragma unroll
    for (int b = 0; b < 8; b++) {
      uv[b] = *(const uint4v*)(Uc + (size_t)id[b].x * FD + lane * 8);
      ev[b] = *(const uint4v*)(Ebf + (size_t)id[b].y * FD + lane * 8);
    }
    float v[8];
#pragma unroll
    for (int b = 0; b < 8; b++) {
      const ushort8 u = *(const ushort8*)&uv[b];
      const ushort8 e = *(const ushort8*)&ev[b];
      float s = 0.f;
#pragma unroll
      for (int q = 0; q < 8; q++) s += bf2f(u[q]) * bf2f(e[q]);
      v[b] = s;
    }
    float w[4];
#pragma unroll
    for (int q = 0; q < 4; q++) {
      const float keep = b1 ? v[2 * q + 1] : v[2 * q];
      const float send = b1 ? v[2 * q] : v[2 * q + 1];
      w[q] = keep + __shfl_xor(send, 1, 64);
    }
    float u2[2];
#pragma unroll
    for (int q = 0; q < 2; q++) {
      const float keep = b2 ? w[2 * q + 1] : w[2 * q];
      const float send = b2 ? w[2 * q] : w[2 * q + 1];
      u2[q] = keep + __shfl_xor(send, 2, 64);
    }
    float f;
    {
      const float keep = b4 ? u2[1] : u2[0];
      const float send = b4 ? u2[0] : u2[1];
      f = keep + __shfl_xor(send, 4, 64);
    }
    f += __shfl_xor(f, 8, 64);
    f += __shfl_xor(f, 16, 64);
    f += __shfl_xor(f, 32, 64);
    if (lane < 8) op[pb + lane] = f;
  }
}

// ---- fallback (tiny workspace): direct fp32, slow but correct ----
__global__ __launch_bounds__(256) void naive_k(const float* __restrict__ emb,
                                               const int* __restrict__ index,
                                               const float* __restrict__ W,
                                               const float* __restrict__ wl,
                                               float* __restrict__ out) {
  __shared__ float bs[FD];
  __shared__ float red[256];
  const int c = blockIdx.y, p = blockIdx.x;
  const int i0 = index[((size_t)c * NPAIRS + p) * 2];
  const int i1 = index[((size_t)c * NPAIRS + p) * 2 + 1];
  const float* wlc = wl + (size_t)c * FD;
  for (int k = threadIdx.x; k < FD; k += 256) bs[k] = emb[(size_t)i1 * FD + k] * wlc[k];
  __syncthreads();
  float s = 0.f;
  for (int n = threadIdx.x; n < FD; n += 256) {
    const float* wr = W + (size_t)n * FD;
    float tacc = 0.f;
    for (int k = 0; k < FD; k++) tacc += wr[k] * bs[k];
    s += tacc * emb[(size_t)i0 * FD + n] * wlc[n];
  }
  red[threadIdx.x] = s;
  __syncthreads();
  for (int st = 128; st > 0; st >>= 1) {
    if (threadIdx.x < st) red[threadIdx.x] += red[threadIdx.x + st];
    __syncthreads();
  }
  if (threadIdx.x == 0) out[(size_t)c * NPAIRS + p] = red[0];
}

extern "C" void kernel_launch(void* const* d_in, const int* in_sizes, int n_in,
                              void* d_out, int out_size, void* d_ws, size_t ws_size,
                              hipStream_t stream) {
  const float* emb = (const float*)d_in[0];
  const int* index = (const int*)d_in[1];
  const float* Wg = (const float*)d_in[2];
  const float* wl = (const float*)d_in[3];
  float* out = (float*)d_out;

  const size_t ebytes = (size_t)NE * FD * 2;  // 4 MiB bf16 embedding
  const size_t wtcell = (size_t)FD * FD * 2;  // 0.5 MiB per-cell Wt
  const size_t ucell = (size_t)NE * FD * 2;   // 4 MiB per-cell U
  size_t avail = ws_size > ebytes ? ws_size - ebytes : 0;
  int G = (int)(avail / (wtcell + ucell));
  if (G > NCELLS) G = NCELLS;

  if (G < 1) {
    naive_k<<<dim3(NPAIRS, NCELLS), 256, 0, stream>>>(emb, index, Wg, wl, out);
    return;
  }

  unsigned short* Ebf = (unsigned short*)d_ws;
  unsigned short* Wt = (unsigned short*)((char*)d_ws + ebytes);
  unsigned short* U = (unsigned short*)((char*)d_ws + ebytes + (size_t)G * wtcell);

  if (G >= NCELLS) {
    // full path: merged init, one gemm (window-mapped), two-pass k-split dot
    init_k<<<dim3(2048 + NCELLS * 256), 256, 0, stream>>>(emb, Ebf, Wg, wl, Wt);
    gemm_k<<<dim3(32 * NCELLS), 512, 0, stream>>>(Ebf, Wt, U);
    dot_p<<<dim3(8 * 320), 256, 0, stream>>>(U, Ebf, index, out);
    return;
  }

  conv_e<<<dim3((NE * FD / 4) / 256), 256, 0, stream>>>(emb, Ebf);
  for (int c0 = 0; c0 < NCELLS; c0 += G) {
    int g = (NCELLS - c0 < G) ? (NCELLS - c0) : G;
    prep_w<<<dim3(FD / 32, FD / 32, g), 256, 0, stream>>>(Wg, wl, Wt, c0);
    gemm_k<<<dim3(32 * g), 512, 0, stream>>>(Ebf, Wt, U);
    dot_k<<<dim3(NPAIRS / 128, g), 256, 0, stream>>>(U, Ebf, index, out, c0);
  }
}

// Round 10
// 219.769 us; speedup vs baseline: 1.3915x; 1.0007x over previous
//
#include <hip/hip_runtime.h>
#include <stdint.h>

#define NE 4096
#define FD 512
#define NCELLS 39
#define NPAIRS 8192
#define NT (FD / 64)  // 8 K-tiles of BK=64

typedef __attribute__((ext_vector_type(8))) short short8;
typedef __attribute__((ext_vector_type(8))) unsigned short ushort8;
typedef __attribute__((ext_vector_type(4))) float f32x4;
typedef __attribute__((ext_vector_type(4))) unsigned int uint4v;

__device__ __forceinline__ unsigned short f2bf(float f) {
  union { float f; uint32_t u; } v; v.f = f;
  uint32_t u = v.u;
  return (unsigned short)((u + 0x7fffu + ((u >> 16) & 1u)) >> 16);  // RNE
}
__device__ __forceinline__ float bf2f(unsigned short b) {
  return __uint_as_float(((uint32_t)b) << 16);
}

__device__ __forceinline__ void async16(const void* g, void* l) {
  __builtin_amdgcn_global_load_lds((const __attribute__((address_space(1))) void*)g,
                                   (__attribute__((address_space(3))) void*)l, 16, 0, 0);
}

// ---- kernel 1 (merged): blocks [0,2048) convert embedding fp32->bf16;
//      blocks [2048,12032) build Wt[ci][k][n] = wl[c,n]*wl[c,k]*W[n,k] (bf16) ----
__global__ __launch_bounds__(256) void init_k(const float* __restrict__ E,
                                              unsigned short* __restrict__ Ebf,
                                              const float* __restrict__ W,
                                              const float* __restrict__ wl,
                                              unsigned short* __restrict__ Wt) {
  __shared__ float tile[32][33];
  const int bid = blockIdx.x;
  if (bid < 2048) {
    const int i = bid * 256 + threadIdx.x;
    const float4 v = ((const float4*)E)[i];
    ushort4 o;
    o.x = f2bf(v.x); o.y = f2bf(v.y); o.z = f2bf(v.z); o.w = f2bf(v.w);
    ((ushort4*)Ebf)[i] = o;
    return;
  }
  const int pid = bid - 2048;
  const int ci = pid >> 8;
  const int rem = pid & 255;
  const int tn = (rem & 15) * 32, tk = (rem >> 4) * 32;
  const int tx = threadIdx.x & 31, ty = threadIdx.x >> 5;
  const float* wlr = wl + (size_t)ci * FD;
#pragma unroll
  for (int i = 0; i < 4; i++) {
    int n = tn + ty + i * 8;
    tile[ty + i * 8][tx] = W[(size_t)n * FD + tk + tx] * wlr[n];
  }
  __syncthreads();
  unsigned short* dst = Wt + (size_t)ci * FD * FD;
#pragma unroll
  for (int i = 0; i < 4; i++) {
    int kout = tk + ty + i * 8;
    dst[(size_t)kout * FD + tn + tx] = f2bf(tile[tx][ty + i * 8] * wlr[kout]);
  }
}

// ---- standalone copies for the chunked fallback path ----
__global__ __launch_bounds__(256) void conv_e(const float* __restrict__ E,
                                              unsigned short* __restrict__ Ebf) {
  const int i = blockIdx.x * 256 + threadIdx.x;
  const float4 v = ((const float4*)E)[i];
  ushort4 o;
  o.x = f2bf(v.x); o.y = f2bf(v.y); o.z = f2bf(v.z); o.w = f2bf(v.w);
  ((ushort4*)Ebf)[i] = o;
}

__global__ __launch_bounds__(256) void prep_w(const float* __restrict__ W,
                                              const float* __restrict__ wl,
                                              unsigned short* __restrict__ Wt,
                                              int c0) {
  __shared__ float tile[32][33];
  const int ci = blockIdx.z;
  const int tn = blockIdx.x * 32, tk = blockIdx.y * 32;
  const int tx = threadIdx.x & 31, ty = threadIdx.x >> 5;
  const float* wlr = wl + (size_t)(c0 + ci) * FD;
#pragma unroll
  for (int i = 0; i < 4; i++) {
    int n = tn + ty + i * 8;
    tile[ty + i * 8][tx] = W[(size_t)n * FD + tk + tx] * wlr[n];
  }
  __syncthreads();
  unsigned short* dst = Wt + (size_t)ci * FD * FD;
#pragma unroll
  for (int i = 0; i < 4; i++) {
    int kout = tk + ty + i * 8;
    dst[(size_t)kout * FD + tn + tx] = f2bf(tile[tx][ty + i * 8] * wlr[kout]);
  }
}

// ---- kernel 3: U[ci][e][k] = sum_n Ebf[e,n] * Wt[ci][k][n]  (bf16 out) ----
// 256x256 8-phase template + window-256 L2-tiled mapping.  At its practical
// floor (~103us) -- seven structural variants all land 102-118us.
__global__ __launch_bounds__(512, 2) void gemm_k(const unsigned short* __restrict__ Ebf,
                                                 const unsigned short* __restrict__ Wt,
                                                 unsigned short* __restrict__ U) {
  __shared__ unsigned short lds[2][2][2][128 * 64];  // [buf][A=0/B=1][half][row*64+col]
  const int t = threadIdx.x;
  const int id = blockIdx.x;
  int bx, by, ci;
  if (gridDim.x == 32 * NCELLS) {
    // full dispatch (1248 blocks): window-256 L2-tiled mapping (bijective)
    if (id < 1024) {
      const int a = id & 7, m = (id >> 3) & 7, h = (id >> 6) & 3, w = id >> 8;
      bx = m | ((a & 1) << 3);
      const int cb = (w << 4) | ((a >> 1) << 2) | h;  // 0..63
      ci = cb >> 1; by = cb & 1;
    } else {
      const int r = id - 1024;  // 0..223 tail: 14 cb x 16 bx
      bx = r & 15;
      const int cb = 64 + (r >> 4);  // 64..77
      ci = cb >> 1; by = cb & 1;
    }
  } else {
    // chunked fallback: round-2 generic mapping (bx pinned per XCD)
    const int xcd = id & 7;
    const int j = id >> 3;
    bx = xcd * 2 + (j & 1);
    by = (j >> 1) & 1;
    ci = j >> 2;
  }

  const unsigned short* Ag = Ebf + (size_t)bx * 256 * FD;
  const unsigned short* Bg = Wt + (size_t)ci * FD * FD + (size_t)by * 256 * FD;

  const int wave = t >> 6, lane = t & 63;
  const int wm = wave >> 2, wn = wave & 3;  // 2M x 4N wave grid
  const int lr = lane & 15, lq = lane >> 4;

  // staging: physical granule pg (row=pg>>3, g=pg&7); source uses g ^ (row&7)
  const int pg0 = t, pg1 = 512 + t;
  const int sr0 = pg0 >> 3, sg0 = pg0 & 7;
  const int sr1 = pg1 >> 3, sg1 = pg1 & 7;
  const int soff0 = sr0 * FD + ((sg0 ^ (sr0 & 7)) << 3);
  const int soff1 = sr1 * FD + ((sg1 ^ (sr1 & 7)) << 3);
  const int loff0 = pg0 * 8, loff1 = pg1 * 8;

  // read swizzle: frag rows always have row%8 == lr%8
  const int swz0 = (lq ^ (lr & 7)) << 3;        // k-slice 0 granule
  const int swz1 = ((4 + lq) ^ (lr & 7)) << 3;  // k-slice 1 granule

#define STAGE(OP, HALF, KT, GBASE)                                                \
  do {                                                                            \
    const int bi_ = (KT) & 1;             /* buffer from UNclamped kt */          \
    const int kt_ = (KT) < NT ? (KT) : (NT - 1); /* clamp src, keep count */      \
    const unsigned short* gb_ = (GBASE) + (size_t)(HALF) * (128 * FD) + kt_ * 64; \
    unsigned short* d_ = &lds[bi_][OP][HALF][0];                                  \
    async16(gb_ + soff0, d_ + loff0);                                             \
    async16(gb_ + soff1, d_ + loff1);                                             \
  } while (0)

  short8 a[8], b01[4], b23[4];
  f32x4 acc[8][4];
#pragma unroll
  for (int i = 0; i < 8; i++)
#pragma unroll
    for (int j2 = 0; j2 < 4; j2++) acc[i][j2] = (f32x4){0.f, 0.f, 0.f, 0.f};

#define LDA(BUF, MSET)                                                  \
  do {                                                                  \
    const unsigned short* p_ = &lds[BUF][0][wm][0];                     \
    _Pragma("unroll") for (int mi_ = 0; mi_ < 4; ++mi_) {               \
      const int row_ = (MSET) * 64 + mi_ * 16 + lr;                     \
      a[mi_ * 2 + 0] = *(const short8*)&p_[row_ * 64 + swz0];           \
      a[mi_ * 2 + 1] = *(const short8*)&p_[row_ * 64 + swz1];           \
    }                                                                   \
  } while (0)

#define LDB(BUF, NSET, DST)                                             \
  do {                                                                  \
    const unsigned short* p_ = &lds[BUF][1][wn >> 1][0];                \
    _Pragma("unroll") for (int ni_ = 0; ni_ < 2; ++ni_) {               \
      const int row_ = (wn & 1) * 64 + ((NSET) * 2 + ni_) * 16 + lr;    \
      (DST)[ni_ * 2 + 0] = *(const short8*)&p_[row_ * 64 + swz0];       \
      (DST)[ni_ * 2 + 1] = *(const short8*)&p_[row_ * 64 + swz1];       \
    }                                                                   \
  } while (0)

#define MMA(MSET, NSET, B)                                                               \
  do {                                                                                   \
    __builtin_amdgcn_s_setprio(1);                                                       \
    _Pragma("unroll") for (int mi_ = 0; mi_ < 4; ++mi_)                                  \
    _Pragma("unroll") for (int ni_ = 0; ni_ < 2; ++ni_)                                  \
    _Pragma("unroll") for (int s_ = 0; s_ < 2; ++s_)                                     \
      acc[(MSET) * 4 + mi_][(NSET) * 2 + ni_] = __builtin_amdgcn_mfma_f32_16x16x32_bf16( \
          a[mi_ * 2 + s_], (B)[ni_ * 2 + s_],                                            \
          acc[(MSET) * 4 + mi_][(NSET) * 2 + ni_], 0, 0, 0);                             \
    __builtin_amdgcn_s_setprio(0);                                                       \
  } while (0)

#define SYNC_LG()                                        \
  do {                                                   \
    __builtin_amdgcn_s_barrier();                        \
    asm volatile("s_waitcnt lgkmcnt(0)" ::: "memory");   \
  } while (0)

  // prologue: all 4 half-tiles of kt0 + B-lo,A-lo of kt1 (6 HTs = 12 loads)
  STAGE(1, 0, 0, Bg); STAGE(0, 0, 0, Ag); STAGE(1, 1, 0, Bg); STAGE(0, 1, 0, Ag);
  STAGE(1, 0, 1, Bg); STAGE(0, 0, 1, Ag);
  asm volatile("s_waitcnt vmcnt(4)" ::: "memory");  // kt0 fully landed
  __builtin_amdgcn_s_barrier();

  for (int it = 0; it < NT / 2; ++it) {
    const int k1 = 2 * it + 1, k2 = 2 * it + 2, k3 = 2 * it + 3;
    // ----- K-tile 2it from buf0 -----
    LDA(0, 0); LDB(0, 0, b01);
    STAGE(1, 1, k1, Bg);
    SYNC_LG(); MMA(0, 0, b01); __builtin_amdgcn_s_barrier();
    LDB(0, 1, b23);
    STAGE(0, 1, k1, Ag);
    SYNC_LG(); MMA(0, 1, b23); __builtin_amdgcn_s_barrier();
    LDA(0, 1);
    STAGE(1, 0, k2, Bg);
    SYNC_LG(); MMA(1, 1, b23); __builtin_amdgcn_s_barrier();
    STAGE(0, 0, k2, Ag);
    __builtin_amdgcn_s_barrier();
    MMA(1, 0, b01);
    asm volatile("s_waitcnt vmcnt(4)" ::: "memory");  // kt1 fully landed
    __builtin_amdgcn_s_barrier();
    // ----- K-tile 2it+1 from buf1 -----
    LDA(1, 0); LDB(1, 0, b01);
    STAGE(1, 1, k2, Bg);
    SYNC_LG(); MMA(0, 0, b01); __builtin_amdgcn_s_barrier();
    LDB(1, 1, b23);
    STAGE(0, 1, k2, Ag);
    SYNC_LG(); MMA(0, 1, b23); __builtin_amdgcn_s_barrier();
    LDA(1, 1);
    STAGE(1, 0, k3, Bg);
    SYNC_LG(); MMA(1, 1, b23); __builtin_amdgcn_s_barrier();
    STAGE(0, 0, k3, Ag);
    __builtin_amdgcn_s_barrier();
    MMA(1, 0, b01);
    asm volatile("s_waitcnt vmcnt(4)" ::: "memory");  // kt2 fully landed
    __builtin_amdgcn_s_barrier();
  }

  // epilogue: direct store
  unsigned short* Up = U + (size_t)ci * NE * FD;
  const int mrow0 = bx * 256 + wm * 128;
  const int ncol0 = by * 256 + wn * 64;
#pragma unroll
  for (int mi = 0; mi < 8; ++mi) {
    const int mbase = mrow0 + mi * 16 + lq * 4;
#pragma unroll
    for (int ni = 0; ni < 4; ++ni) {
      const int n = ncol0 + ni * 16 + lr;
#pragma unroll
      for (int r = 0; r < 4; ++r)
        Up[(size_t)(mbase + r) * FD + n] = f2bf(acc[mi][ni][r]);
    }
  }
#undef STAGE
#undef LDA
#undef LDB
#undef MMA
#undef SYNC_LG
}

// ---- kernel 4 (full path): PERSISTENT cell-sequential k-split dot ----
// 128 blocks/XCD (1024 total, 4/CU, 16 waves/CU -- whole grid co-resident).
// Each block loops h (outer) -> cell (inner) over its XCD's 4-5 cells, so at
// any time one XCD touches only U[c] half (2MB) + E half (2MB) = 4MB = one L2
// (r9's flat grid had all 5 cells concurrent: 12MB -> thrash).  E-half fetched
// once per pass; U halves stream one cell at a time.  h=0 partials in accb[5]
// (unrolled -> static idx).  Inner 16-pair body identical to r9 (verified).
__global__ __launch_bounds__(256) void dot_q(const unsigned short* __restrict__ U,
                                             const unsigned short* __restrict__ Ebf,
                                             const int* __restrict__ index,
                                             float* __restrict__ out) {
  const int id = blockIdx.x;
  const int xcd = id & 7;
  const int pairblock = id >> 3;    // 0..127
  const int ncx = (xcd < 7) ? 5 : 4;

  const int wave = threadIdx.x >> 6, lane = threadIdx.x & 63;
  const int l5 = lane & 31, psub = lane >> 5;
  const int pb = pairblock * 64 + wave * 16;

  const int b1 = lane & 1, b2 = (lane >> 1) & 1, b4 = (lane >> 2) & 1;

  float accb[5];
#pragma unroll
  for (int h = 0; h < 2; ++h) {
    const int off = h * 256;
#pragma unroll
    for (int cs = 0; cs < 5; ++cs) {
      if (cs < ncx) {
        const int ci = xcd + 8 * cs;
        const unsigned short* Uc = U + (size_t)ci * NE * FD;
        const size_t cp = (size_t)ci * NPAIRS;
        const int2* idx2 = (const int2*)index + cp;
        int2 id8[8];
#pragma unroll
        for (int b = 0; b < 8; b++) id8[b] = idx2[pb + 2 * b + psub];
        uint4v uv[8], ev[8];
#pragma unroll
        for (int b = 0; b < 8; b++) {
          uv[b] = *(const uint4v*)(Uc + (size_t)id8[b].x * FD + off + l5 * 8);
          ev[b] = *(const uint4v*)(Ebf + (size_t)id8[b].y * FD + off + l5 * 8);
        }
        float v[8];
#pragma unroll
        for (int b = 0; b < 8; b++) {
          const ushort8 u = *(const ushort8*)&uv[b];
          const ushort8 e = *(const ushort8*)&ev[b];
          float s = 0.f;
#pragma unroll
          for (int q = 0; q < 8; q++) s += bf2f(u[q]) * bf2f(e[q]);
          v[b] = s;
        }
        // fold pair-register bits into lane bits 0-2
        float w[4];
#pragma unroll
        for (int q = 0; q < 4; q++) {
          const float keep = b1 ? v[2 * q + 1] : v[2 * q];
          const float send = b1 ? v[2 * q] : v[2 * q + 1];
          w[q] = keep + __shfl_xor(send, 1, 64);
        }
        float u2[2];
#pragma unroll
        for (int q = 0; q < 2; q++) {
          const float keep = b2 ? w[2 * q + 1] : w[2 * q];
          const float send = b2 ? w[2 * q] : w[2 * q + 1];
          u2[q] = keep + __shfl_xor(send, 2, 64);
        }
        float f;
        {
          const float keep = b4 ? u2[1] : u2[0];
          const float send = b4 ? u2[0] : u2[1];
          f = keep + __shfl_xor(send, 4, 64);
        }
        // reduce remaining lane bits 3,4 (bit 5 = pair-subgroup, untouched)
        f += __shfl_xor(f, 8, 64);
        f += __shfl_xor(f, 16, 64);
        if (h == 0) {
          accb[cs] = f;
        } else if ((lane & 24) == 0) {
          out[cp + pb + ((lane & 7) * 2 + psub)] = accb[cs] + f;
        }
      }
    }
  }
}

// ---- kernel 4b (chunked fallback): original 2-D mapping ----
__global__ __launch_bounds__(256) void dot_k(const unsigned short* __restrict__ U,
                                             const unsigned short* __restrict__ Ebf,
                                             const int* __restrict__ index,
                                             float* __restrict__ out,
                                             int c0) {
  const int ci = blockIdx.y;
  const int c = c0 + ci;
  const int wave = threadIdx.x >> 6, lane = threadIdx.x & 63;
  const unsigned short* Uc = U + (size_t)ci * NE * FD;
  const size_t cp = (size_t)c * NPAIRS;
  const int2* idx2 = (const int2*)index + cp;
  float* op = out + cp;
  const int pbase = (blockIdx.x * 4 + wave) * 32;

  const int b1 = lane & 1, b2 = (lane >> 1) & 1, b4 = (lane >> 2) & 1;

  for (int batch = 0; batch < 4; batch++) {
    const int pb = pbase + batch * 8;
    int2 id[8];
#pragma unroll
    for (int b = 0; b < 8; b++) id[b] = idx2[pb + b];
    uint4v uv[8], ev[8];
#pragma unroll
    for (int b = 0; b < 8; b++) {
      uv[b] = *(const uint4v*)(Uc + (size_t)id[b].x * FD + lane * 8);
      ev[b] = *(const uint4v*)(Ebf + (size_t)id[b].y * FD + lane * 8);
    }
    float v[8];
#pragma unroll
    for (int b = 0; b < 8; b++) {
      const ushort8 u = *(const ushort8*)&uv[b];
      const ushort8 e = *(const ushort8*)&ev[b];
      float s = 0.f;
#pragma unroll
      for (int q = 0; q < 8; q++) s += bf2f(u[q]) * bf2f(e[q]);
      v[b] = s;
    }
    float w[4];
#pragma unroll
    for (int q = 0; q < 4; q++) {
      const float keep = b1 ? v[2 * q + 1] : v[2 * q];
      const float send = b1 ? v[2 * q] : v[2 * q + 1];
      w[q] = keep + __shfl_xor(send, 1, 64);
    }
    float u2[2];
#pragma unroll
    for (int q = 0; q < 2; q++) {
      const float keep = b2 ? w[2 * q + 1] : w[2 * q];
      const float send = b2 ? w[2 * q] : w[2 * q + 1];
      u2[q] = keep + __shfl_xor(send, 2, 64);
    }
    float f;
    {
      const float keep = b4 ? u2[1] : u2[0];
      const float send = b4 ? u2[0] : u2[1];
      f = keep + __shfl_xor(send, 4, 64);
    }
    f += __shfl_xor(f, 8, 64);
    f += __shfl_xor(f, 16, 64);
    f += __shfl_xor(f, 32, 64);
    if (lane < 8) op[pb + lane] = f;
  }
}

// ---- fallback (tiny workspace): direct fp32, slow but correct ----
__global__ __launch_bounds__(256) void naive_k(const float* __restrict__ emb,
                                               const int* __restrict__ index,
                                               const float* __restrict__ W,
                                               const float* __restrict__ wl,
                                               float* __restrict__ out) {
  __shared__ float bs[FD];
  __shared__ float red[256];
  const int c = blockIdx.y, p = blockIdx.x;
  const int i0 = index[((size_t)c * NPAIRS + p) * 2];
  const int i1 = index[((size_t)c * NPAIRS + p) * 2 + 1];
  const float* wlc = wl + (size_t)c * FD;
  for (int k = threadIdx.x; k < FD; k += 256) bs[k] = emb[(size_t)i1 * FD + k] * wlc[k];
  __syncthreads();
  float s = 0.f;
  for (int n = threadIdx.x; n < FD; n += 256) {
    const float* wr = W + (size_t)n * FD;
    float tacc = 0.f;
    for (int k = 0; k < FD; k++) tacc += wr[k] * bs[k];
    s += tacc * emb[(size_t)i0 * FD + n] * wlc[n];
  }
  red[threadIdx.x] = s;
  __syncthreads();
  for (int st = 128; st > 0; st >>= 1) {
    if (threadIdx.x < st) red[threadIdx.x] += red[threadIdx.x + st];
    __syncthreads();
  }
  if (threadIdx.x == 0) out[(size_t)c * NPAIRS + p] = red[0];
}

extern "C" void kernel_launch(void* const* d_in, const int* in_sizes, int n_in,
                              void* d_out, int out_size, void* d_ws, size_t ws_size,
                              hipStream_t stream) {
  const float* emb = (const float*)d_in[0];
  const int* index = (const int*)d_in[1];
  const float* Wg = (const float*)d_in[2];
  const float* wl = (const float*)d_in[3];
  float* out = (float*)d_out;

  const size_t ebytes = (size_t)NE * FD * 2;  // 4 MiB bf16 embedding
  const size_t wtcell = (size_t)FD * FD * 2;  // 0.5 MiB per-cell Wt
  const size_t ucell = (size_t)NE * FD * 2;   // 4 MiB per-cell U
  size_t avail = ws_size > ebytes ? ws_size - ebytes : 0;
  int G = (int)(avail / (wtcell + ucell));
  if (G > NCELLS) G = NCELLS;

  if (G < 1) {
    naive_k<<<dim3(NPAIRS, NCELLS), 256, 0, stream>>>(emb, index, Wg, wl, out);
    return;
  }

  unsigned short* Ebf = (unsigned short*)d_ws;
  unsigned short* Wt = (unsigned short*)((char*)d_ws + ebytes);
  unsigned short* U = (unsigned short*)((char*)d_ws + ebytes + (size_t)G * wtcell);

  if (G >= NCELLS) {
    // full path: merged init, one gemm (window-mapped), persistent k-split dot
    init_k<<<dim3(2048 + NCELLS * 256), 256, 0, stream>>>(emb, Ebf, Wg, wl, Wt);
    gemm_k<<<dim3(32 * NCELLS), 512, 0, stream>>>(Ebf, Wt, U);
    dot_q<<<dim3(1024), 256, 0, stream>>>(U, Ebf, index, out);
    return;
  }

  conv_e<<<dim3((NE * FD / 4) / 256), 256, 0, stream>>>(emb, Ebf);
  for (int c0 = 0; c0 < NCELLS; c0 += G) {
    int g = (NCELLS - c0 < G) ? (NCELLS - c0) : G;
    prep_w<<<dim3(FD / 32, FD / 32, g), 256, 0, stream>>>(Wg, wl, Wt, c0);
    gemm_k<<<dim3(32 * g), 512, 0, stream>>>(Ebf, Wt, U);
    dot_k<<<dim3(NPAIRS / 128, g), 256, 0, stream>>>(U, Ebf, index, out, c0);
  }
}